// Round 1
// baseline (2810.441 us; speedup 1.0000x reference)
//
#include <hip/hip_runtime.h>

// GCN 2-layer: agg = segment_sum(x[src], dst); h = relu((agg*inv_deg)@W1+b1);
// agg2 = segment_sum(h[src], dst); out = (agg2*inv_deg)@W2+b2
// N=50000 nodes, E=800000 edges, F 128->128->64, fp32.

constexpr int NNODES = 50000;
constexpr int NEDGES = 800000;

// ---------------------------------------------------------------------------
// Scatter-add: one 32-lane group per edge; each lane moves 4 contiguous floats
// (float4 gather from x[src], 4 fp32 atomics into agg[dst]).
// Optionally counts in-degree (lane 0 of each group) for layer 1.
// ---------------------------------------------------------------------------
__global__ __launch_bounds__(256) void scatter_kernel(
    const float* __restrict__ x, const int* __restrict__ src,
    const int* __restrict__ dst, float* __restrict__ agg,
    float* __restrict__ deg, int nEdges)
{
    int t = blockIdx.x * blockDim.x + threadIdx.x;
    int e = t >> 5;
    if (e >= nEdges) return;
    int c = (t & 31) << 2;
    int s = src[e];
    int d = dst[e];
    float4 v = *reinterpret_cast<const float4*>(x + (size_t)s * 128 + c);
    float* p = agg + (size_t)d * 128 + c;
    atomicAdd(p + 0, v.x);
    atomicAdd(p + 1, v.y);
    atomicAdd(p + 2, v.z);
    atomicAdd(p + 3, v.w);
    if (deg != nullptr && (t & 31) == 0) atomicAdd(&deg[d], 1.0f);
}

// deg[i] -> 1/max(deg[i],1), in place
__global__ __launch_bounds__(256) void inv_kernel(float* __restrict__ deg, int n)
{
    int i = blockIdx.x * blockDim.x + threadIdx.x;
    if (i < n) deg[i] = 1.0f / fmaxf(deg[i], 1.0f);
}

// ---------------------------------------------------------------------------
// Row-normalized GEMM + bias (+ optional relu):
//   out[r][c] = relu( sum_k A[r][k]*inv_deg[r] * W[k][c] + b[c] )
// K = 128 fixed. Each thread computes a 4x4 register tile. A-tile staged in
// LDS (pad +4 -> broadcast reads conflict-free / 2-way max). W read as
// coalesced float4 rows (L1/L2-hot: W1=64KB, W2=32KB).
// ---------------------------------------------------------------------------
template<int OUT, bool RELU>
__global__ __launch_bounds__(256) void gemm_kernel(
    const float* __restrict__ A, const float* __restrict__ inv_deg,
    const float* __restrict__ W, const float* __restrict__ bias,
    float* __restrict__ out, int nrows)
{
    constexpr int CG = OUT / 4;        // thread-groups along columns
    constexpr int RGROUPS = 256 / CG;  // row groups per block
    constexpr int ROWS = RGROUPS * 4;  // rows per block
    constexpr int LDK = 132;           // +4 pad: rows land 4 banks apart
    __shared__ float lds_a[ROWS][LDK];

    const int row0 = blockIdx.x * ROWS;
    const int cg = threadIdx.x % CG;
    const int col = cg * 4;
    const int rg = threadIdx.x / CG;
    const int rbase = rg * 4;

    // stage A*inv_deg into LDS, float4 per thread per iter
    for (int i = threadIdx.x * 4; i < ROWS * 128; i += 256 * 4) {
        const int r = i >> 7;
        const int k = i & 127;
        const int row = row0 + r;
        float4 v = make_float4(0.f, 0.f, 0.f, 0.f);
        if (row < nrows) {
            v = *reinterpret_cast<const float4*>(A + (size_t)row * 128 + k);
            const float s = inv_deg[row];
            v.x *= s; v.y *= s; v.z *= s; v.w *= s;
        }
        *reinterpret_cast<float4*>(&lds_a[r][k]) = v;
    }
    __syncthreads();

    float acc[4][4] = {};
    #pragma unroll 4
    for (int k = 0; k < 128; ++k) {
        const float4 w = *reinterpret_cast<const float4*>(W + k * OUT + col);
        #pragma unroll
        for (int r = 0; r < 4; ++r) {
            const float a = lds_a[rbase + r][k];
            acc[r][0] += a * w.x;
            acc[r][1] += a * w.y;
            acc[r][2] += a * w.z;
            acc[r][3] += a * w.w;
        }
    }

    const float4 bv = *reinterpret_cast<const float4*>(bias + col);
    #pragma unroll
    for (int r = 0; r < 4; ++r) {
        const int row = row0 + rbase + r;
        if (row >= nrows) continue;
        float4 o;
        o.x = acc[r][0] + bv.x;
        o.y = acc[r][1] + bv.y;
        o.z = acc[r][2] + bv.z;
        o.w = acc[r][3] + bv.w;
        if (RELU) {
            o.x = fmaxf(o.x, 0.f); o.y = fmaxf(o.y, 0.f);
            o.z = fmaxf(o.z, 0.f); o.w = fmaxf(o.w, 0.f);
        }
        *reinterpret_cast<float4*>(out + (size_t)row * OUT + col) = o;
    }
}

extern "C" void kernel_launch(void* const* d_in, const int* in_sizes, int n_in,
                              void* d_out, int out_size, void* d_ws, size_t ws_size,
                              hipStream_t stream)
{
    const float* x  = (const float*)d_in[0];
    const int*   src = (const int*)d_in[1];
    const int*   dst = (const int*)d_in[2];
    const float* W1 = (const float*)d_in[3];
    const float* b1 = (const float*)d_in[4];
    const float* W2 = (const float*)d_in[5];
    const float* b2 = (const float*)d_in[6];
    float* out = (float*)d_out;

    // workspace layout (floats):
    //   [0, N)                 deg -> inv_deg (in place)
    //   [51200, 51200+N*128)   agg (reused for both layers)
    //   [.., +N*128)           h
    float* ws  = (float*)d_ws;
    float* deg = ws;
    float* agg = ws + 51200;
    float* h   = ws + 51200 + (size_t)NNODES * 128;

    // zero deg + agg in one memset (contiguous region)
    hipMemsetAsync(d_ws, 0, (size_t)(51200 + NNODES * 128) * sizeof(float), stream);

    const int scatterBlocks = (NEDGES * 32 + 255) / 256;  // 100000

    // layer 1: aggregate x (and count degree), normalize+GEMM+relu
    scatter_kernel<<<scatterBlocks, 256, 0, stream>>>(x, src, dst, agg, deg, NEDGES);
    inv_kernel<<<(NNODES + 255) / 256, 256, 0, stream>>>(deg, NNODES);
    gemm_kernel<128, true><<<(NNODES + 31) / 32, 256, 0, stream>>>(
        agg, deg, W1, b1, h, NNODES);

    // layer 2: re-zero agg, aggregate h, normalize+GEMM
    hipMemsetAsync(agg, 0, (size_t)NNODES * 128 * sizeof(float), stream);
    scatter_kernel<<<scatterBlocks, 256, 0, stream>>>(h, src, dst, agg, nullptr, NEDGES);
    gemm_kernel<64, false><<<(NNODES + 63) / 64, 256, 0, stream>>>(
        agg, deg, W2, b2, out, NNODES);
}

// Round 2
// 378.304 us; speedup vs baseline: 7.4291x; 7.4291x over previous
//
#include <hip/hip_runtime.h>

// GCN 2-layer via per-call CSR build + gather-aggregate (no fp32 atomics).
//   deg/rowStart from dst histogram + scan; csr_src via int-atomic binning.
//   agg1 = gather_sum(x)            [128-wide]
//   h    = relu((agg1*inv_deg)@W1+b1)   (in-place GEMM)
//   y2   = h@W2                     [GEMM-first: row-scale commutes with @W]
//   out  = gather_sum(y2)*inv_deg + b2  [64-wide]

constexpr int NNODES = 50000;
constexpr int NEDGES = 800000;

// ---------------------------------------------------------------------------
__global__ __launch_bounds__(256) void hist_kernel(
    const int* __restrict__ dst, int* __restrict__ degi, int n)
{
    int i = blockIdx.x * blockDim.x + threadIdx.x;
    if (i < n) atomicAdd(&degi[dst[i]], 1);
}

// Single-block exclusive scan over deg -> rowStart, fill (=rowStart copy),
// inv_deg = 1/max(deg,1).
__global__ __launch_bounds__(1024) void scan_kernel(
    const int* __restrict__ degi, int* __restrict__ rowStart,
    int* __restrict__ fill, float* __restrict__ inv_deg, int n)
{
    __shared__ int lds[1024];
    const int t = threadIdx.x;
    const int per = (n + 1023) / 1024;
    const int lo = min(t * per, n);
    const int hi = min(lo + per, n);
    int sum = 0;
    for (int i = lo; i < hi; ++i) sum += degi[i];
    lds[t] = sum;
    __syncthreads();
    for (int off = 1; off < 1024; off <<= 1) {
        int o = (t >= off) ? lds[t - off] : 0;
        __syncthreads();
        lds[t] += o;
        __syncthreads();
    }
    int run = (t == 0) ? 0 : lds[t - 1];
    for (int i = lo; i < hi; ++i) {
        rowStart[i] = run;
        fill[i] = run;
        const int d = degi[i];
        inv_deg[i] = 1.0f / fmaxf((float)d, 1.0f);
        run += d;
    }
    if (hi == n) rowStart[n] = run;  // all trailing threads write total; benign
}

__global__ __launch_bounds__(256) void permute_kernel(
    const int* __restrict__ src, const int* __restrict__ dst,
    int* __restrict__ fill, int* __restrict__ csr, int n)
{
    int i = blockIdx.x * blockDim.x + threadIdx.x;
    if (i < n) {
        int slot = atomicAdd(&fill[dst[i]], 1);
        csr[slot] = src[i];
    }
}

// ---------------------------------------------------------------------------
// One wave per dst node. 64 lanes = EPW edge-slots x LPR float4 column groups.
// Register accumulate over the node's edge list, shuffle-reduce across edge
// slots, single coalesced row write. EPI: fuse *inv_deg + bias (layer-2 tail).
// ---------------------------------------------------------------------------
template<int F, bool EPI>
__global__ __launch_bounds__(256) void gather_agg_kernel(
    const float* __restrict__ feat, const int* __restrict__ csr,
    const int* __restrict__ rowStart, const float* __restrict__ inv_deg,
    const float* __restrict__ bias, float* __restrict__ out, int nNodes)
{
    constexpr int LPR = F / 4;     // lanes per row: 32 (F=128) / 16 (F=64)
    constexpr int EPW = 64 / LPR;  // edges in parallel per wave: 2 / 4
    const int wid = (blockIdx.x * blockDim.x + threadIdx.x) >> 6;
    if (wid >= nNodes) return;
    const int lane = threadIdx.x & 63;
    const int eslot = lane / LPR;
    const int c = (lane % LPR) * 4;
    const int rs = rowStart[wid];
    const int re = rowStart[wid + 1];

    float4 acc = make_float4(0.f, 0.f, 0.f, 0.f);
    for (int j = rs + eslot; j < re; j += EPW) {
        const int s = csr[j];
        const float4 v = *reinterpret_cast<const float4*>(feat + (size_t)s * F + c);
        acc.x += v.x; acc.y += v.y; acc.z += v.z; acc.w += v.w;
    }
    #pragma unroll
    for (int off = LPR; off < 64; off <<= 1) {
        acc.x += __shfl_down(acc.x, off, 64);
        acc.y += __shfl_down(acc.y, off, 64);
        acc.z += __shfl_down(acc.z, off, 64);
        acc.w += __shfl_down(acc.w, off, 64);
    }
    if (lane < LPR) {
        if constexpr (EPI) {
            const float s = inv_deg[wid];
            const float4 b = *reinterpret_cast<const float4*>(bias + c);
            acc.x = acc.x * s + b.x; acc.y = acc.y * s + b.y;
            acc.z = acc.z * s + b.z; acc.w = acc.w * s + b.w;
        }
        *reinterpret_cast<float4*>(out + (size_t)wid * F + c) = acc;
    }
}

// ---------------------------------------------------------------------------
// GEMM, K=128 fixed, 4x4 register tile per thread, A staged in LDS (+4 pad).
// SCALE: multiply A rows by inv_deg during staging. BIAS/RELU in epilogue.
// Safe in-place (out==A): blocks own disjoint rows, staged to LDS first.
// ---------------------------------------------------------------------------
template<int OUT, bool SCALE, bool BIAS, bool RELU>
__global__ __launch_bounds__(256) void gemm_kernel(
    const float* __restrict__ A, const float* __restrict__ inv_deg,
    const float* __restrict__ W, const float* __restrict__ bias,
    float* __restrict__ out, int nrows)
{
    constexpr int CG = OUT / 4;
    constexpr int RGROUPS = 256 / CG;
    constexpr int ROWS = RGROUPS * 4;
    constexpr int LDK = 132;
    __shared__ float lds_a[ROWS][LDK];

    const int row0 = blockIdx.x * ROWS;
    const int col = (threadIdx.x % CG) * 4;
    const int rbase = (threadIdx.x / CG) * 4;

    for (int i = threadIdx.x * 4; i < ROWS * 128; i += 256 * 4) {
        const int r = i >> 7;
        const int k = i & 127;
        const int row = row0 + r;
        float4 v = make_float4(0.f, 0.f, 0.f, 0.f);
        if (row < nrows) {
            v = *reinterpret_cast<const float4*>(A + (size_t)row * 128 + k);
            if constexpr (SCALE) {
                const float s = inv_deg[row];
                v.x *= s; v.y *= s; v.z *= s; v.w *= s;
            }
        }
        *reinterpret_cast<float4*>(&lds_a[r][k]) = v;
    }
    __syncthreads();

    float acc[4][4] = {};
    #pragma unroll 4
    for (int k = 0; k < 128; ++k) {
        const float4 w = *reinterpret_cast<const float4*>(W + k * OUT + col);
        #pragma unroll
        for (int r = 0; r < 4; ++r) {
            const float a = lds_a[rbase + r][k];
            acc[r][0] += a * w.x;
            acc[r][1] += a * w.y;
            acc[r][2] += a * w.z;
            acc[r][3] += a * w.w;
        }
    }

    float4 bv = make_float4(0.f, 0.f, 0.f, 0.f);
    if constexpr (BIAS) bv = *reinterpret_cast<const float4*>(bias + col);
    #pragma unroll
    for (int r = 0; r < 4; ++r) {
        const int row = row0 + rbase + r;
        if (row >= nrows) continue;
        float4 o;
        o.x = acc[r][0] + bv.x;
        o.y = acc[r][1] + bv.y;
        o.z = acc[r][2] + bv.z;
        o.w = acc[r][3] + bv.w;
        if constexpr (RELU) {
            o.x = fmaxf(o.x, 0.f); o.y = fmaxf(o.y, 0.f);
            o.z = fmaxf(o.z, 0.f); o.w = fmaxf(o.w, 0.f);
        }
        *reinterpret_cast<float4*>(out + (size_t)row * OUT + col) = o;
    }
}

// ---------------------------------------------------------------------------
extern "C" void kernel_launch(void* const* d_in, const int* in_sizes, int n_in,
                              void* d_out, int out_size, void* d_ws, size_t ws_size,
                              hipStream_t stream)
{
    const float* x   = (const float*)d_in[0];
    const int*   src = (const int*)d_in[1];
    const int*   dst = (const int*)d_in[2];
    const float* W1  = (const float*)d_in[3];
    const float* b1  = (const float*)d_in[4];
    const float* W2  = (const float*)d_in[5];
    const float* b2  = (const float*)d_in[6];
    float* out = (float*)d_out;

    // workspace layout (4B words), total ~42.4 MB
    float* ws  = (float*)d_ws;
    int*   wsi = (int*)d_ws;
    int*   degi     = wsi + 0;        //   50000
    float* invdeg   = ws  + 50048;    //   50000
    int*   rowStart = wsi + 100096;   //   50001
    int*   fill     = wsi + 150160;   //   50000
    int*   csr      = wsi + 200160;   //  800000
    float* aggA     = ws  + 1000160;  // 6400000 (agg1 -> h in place)
    float* y2       = ws  + 7400160;  // 3200000

    hipMemsetAsync(degi, 0, NNODES * sizeof(int), stream);

    const int eb = (NEDGES + 255) / 256;
    hist_kernel<<<eb, 256, 0, stream>>>(dst, degi, NEDGES);
    scan_kernel<<<1, 1024, 0, stream>>>(degi, rowStart, fill, invdeg, NNODES);
    permute_kernel<<<eb, 256, 0, stream>>>(src, dst, fill, csr, NEDGES);

    // layer 1: aggregate x, then in-place normalize+GEMM+bias+relu
    gather_agg_kernel<128, false><<<(NNODES + 3) / 4, 256, 0, stream>>>(
        x, csr, rowStart, nullptr, nullptr, aggA, NNODES);
    gemm_kernel<128, true, true, true><<<(NNODES + 31) / 32, 256, 0, stream>>>(
        aggA, invdeg, W1, b1, aggA, NNODES);

    // layer 2 (GEMM-first): y2 = h@W2, then aggregate+scale+bias
    gemm_kernel<64, false, false, false><<<(NNODES + 63) / 64, 256, 0, stream>>>(
        aggA, nullptr, W2, nullptr, y2, NNODES);
    gather_agg_kernel<64, true><<<(NNODES + 3) / 4, 256, 0, stream>>>(
        y2, csr, rowStart, invdeg, b2, out, NNODES);
}

// Round 3
// 254.041 us; speedup vs baseline: 11.0629x; 1.4891x over previous
//
#include <hip/hip_runtime.h>

// GCN 2-layer via per-call CSR build + gather-aggregate (no fp32 atomics).
//   deg/rowStart from dst histogram + parallel scan; csr_src via int binning.
//   agg1 = gather_sum(x)                 [128-wide]
//   h    = relu((agg1*inv_deg)@W1+b1)    (in-place GEMM)
//   y2   = h@W2                          [GEMM-first: row-scale commutes with @W]
//   out  = gather_sum(y2)*inv_deg + b2   [64-wide]

constexpr int NNODES = 50000;
constexpr int NEDGES = 800000;
constexpr int SCAN_BLOCKS = (NNODES + 255) / 256;  // 196 (must be <= 256)

// ---------------------------------------------------------------------------
__global__ __launch_bounds__(256) void hist_kernel(
    const int* __restrict__ dst, int* __restrict__ degi, int n)
{
    int i = blockIdx.x * blockDim.x + threadIdx.x;
    if (i < n) atomicAdd(&degi[dst[i]], 1);
}

// per-block sum of degi chunk -> blockSum[b]
__global__ __launch_bounds__(256) void partial_kernel(
    const int* __restrict__ degi, int* __restrict__ blockSum, int n)
{
    const int i = blockIdx.x * 256 + threadIdx.x;
    int v = (i < n) ? degi[i] : 0;
    #pragma unroll
    for (int off = 32; off > 0; off >>= 1) v += __shfl_down(v, off, 64);
    __shared__ int lds[4];
    if ((threadIdx.x & 63) == 0) lds[threadIdx.x >> 6] = v;
    __syncthreads();
    if (threadIdx.x == 0)
        blockSum[blockIdx.x] = lds[0] + lds[1] + lds[2] + lds[3];
}

// block-local scan + in-block scan of blockSums -> rowStart, fill, inv_deg
__global__ __launch_bounds__(256) void finalize_kernel(
    const int* __restrict__ degi, const int* __restrict__ blockSum,
    int nBlocks, int* __restrict__ rowStart, int* __restrict__ fill,
    float* __restrict__ inv_deg, int n)
{
    __shared__ int lds[256];
    __shared__ int bs[256];
    const int t = threadIdx.x;
    const int i = blockIdx.x * 256 + t;
    const int d = (i < n) ? degi[i] : 0;
    lds[t] = d;
    bs[t] = (t < nBlocks) ? blockSum[t] : 0;
    __syncthreads();
    #pragma unroll
    for (int off = 1; off < 256; off <<= 1) {
        const int o = (t >= off) ? lds[t - off] : 0;
        __syncthreads();
        lds[t] += o;
        __syncthreads();
    }
    #pragma unroll
    for (int off = 1; off < 256; off <<= 1) {
        const int o = (t >= off) ? bs[t - off] : 0;
        __syncthreads();
        bs[t] += o;
        __syncthreads();
    }
    const int boff = (blockIdx.x == 0) ? 0 : bs[blockIdx.x - 1];
    if (i < n) {
        const int excl = boff + lds[t] - d;
        rowStart[i] = excl;
        fill[i] = excl;
        inv_deg[i] = 1.0f / fmaxf((float)d, 1.0f);
        if (i == n - 1) rowStart[n] = boff + lds[t];
    }
}

__global__ __launch_bounds__(256) void permute_kernel(
    const int* __restrict__ src, const int* __restrict__ dst,
    int* __restrict__ fill, int* __restrict__ csr, int n)
{
    int i = blockIdx.x * blockDim.x + threadIdx.x;
    if (i < n) {
        int slot = atomicAdd(&fill[dst[i]], 1);
        csr[slot] = src[i];
    }
}

// ---------------------------------------------------------------------------
// One wave per dst node. 64 lanes = EPW edge-slots x LPR float4 column groups.
// Register accumulate over the node's edge list, shuffle-reduce across edge
// slots, single coalesced row write. EPI: fuse *inv_deg + bias (layer-2 tail).
// ---------------------------------------------------------------------------
template<int F, bool EPI>
__global__ __launch_bounds__(256) void gather_agg_kernel(
    const float* __restrict__ feat, const int* __restrict__ csr,
    const int* __restrict__ rowStart, const float* __restrict__ inv_deg,
    const float* __restrict__ bias, float* __restrict__ out, int nNodes)
{
    constexpr int LPR = F / 4;     // lanes per row: 32 (F=128) / 16 (F=64)
    constexpr int EPW = 64 / LPR;  // edges in parallel per wave: 2 / 4
    const int wid = (blockIdx.x * blockDim.x + threadIdx.x) >> 6;
    if (wid >= nNodes) return;
    const int lane = threadIdx.x & 63;
    const int eslot = lane / LPR;
    const int c = (lane % LPR) * 4;
    const int rs = rowStart[wid];
    const int re = rowStart[wid + 1];

    float4 acc = make_float4(0.f, 0.f, 0.f, 0.f);
    for (int j = rs + eslot; j < re; j += EPW) {
        const int s = csr[j];
        const float4 v = *reinterpret_cast<const float4*>(feat + (size_t)s * F + c);
        acc.x += v.x; acc.y += v.y; acc.z += v.z; acc.w += v.w;
    }
    #pragma unroll
    for (int off = LPR; off < 64; off <<= 1) {
        acc.x += __shfl_down(acc.x, off, 64);
        acc.y += __shfl_down(acc.y, off, 64);
        acc.z += __shfl_down(acc.z, off, 64);
        acc.w += __shfl_down(acc.w, off, 64);
    }
    if (lane < LPR) {
        if constexpr (EPI) {
            const float s = inv_deg[wid];
            const float4 b = *reinterpret_cast<const float4*>(bias + c);
            acc.x = acc.x * s + b.x; acc.y = acc.y * s + b.y;
            acc.z = acc.z * s + b.z; acc.w = acc.w * s + b.w;
        }
        *reinterpret_cast<float4*>(out + (size_t)wid * F + c) = acc;
    }
}

// ---------------------------------------------------------------------------
// GEMM, K=128 fixed, 4x4 register tile per thread, A staged in LDS (+4 pad).
// SCALE: multiply A rows by inv_deg during staging. BIAS/RELU in epilogue.
// Safe in-place (out==A): blocks own disjoint rows, staged to LDS first.
// ---------------------------------------------------------------------------
template<int OUT, bool SCALE, bool BIAS, bool RELU>
__global__ __launch_bounds__(256) void gemm_kernel(
    const float* __restrict__ A, const float* __restrict__ inv_deg,
    const float* __restrict__ W, const float* __restrict__ bias,
    float* __restrict__ out, int nrows)
{
    constexpr int CG = OUT / 4;
    constexpr int RGROUPS = 256 / CG;
    constexpr int ROWS = RGROUPS * 4;
    constexpr int LDK = 132;
    __shared__ float lds_a[ROWS][LDK];

    const int row0 = blockIdx.x * ROWS;
    const int col = (threadIdx.x % CG) * 4;
    const int rbase = (threadIdx.x / CG) * 4;

    for (int i = threadIdx.x * 4; i < ROWS * 128; i += 256 * 4) {
        const int r = i >> 7;
        const int k = i & 127;
        const int row = row0 + r;
        float4 v = make_float4(0.f, 0.f, 0.f, 0.f);
        if (row < nrows) {
            v = *reinterpret_cast<const float4*>(A + (size_t)row * 128 + k);
            if constexpr (SCALE) {
                const float s = inv_deg[row];
                v.x *= s; v.y *= s; v.z *= s; v.w *= s;
            }
        }
        *reinterpret_cast<float4*>(&lds_a[r][k]) = v;
    }
    __syncthreads();

    float acc[4][4] = {};
    #pragma unroll 4
    for (int k = 0; k < 128; ++k) {
        const float4 w = *reinterpret_cast<const float4*>(W + k * OUT + col);
        #pragma unroll
        for (int r = 0; r < 4; ++r) {
            const float a = lds_a[rbase + r][k];
            acc[r][0] += a * w.x;
            acc[r][1] += a * w.y;
            acc[r][2] += a * w.z;
            acc[r][3] += a * w.w;
        }
    }

    float4 bv = make_float4(0.f, 0.f, 0.f, 0.f);
    if constexpr (BIAS) bv = *reinterpret_cast<const float4*>(bias + col);
    #pragma unroll
    for (int r = 0; r < 4; ++r) {
        const int row = row0 + rbase + r;
        if (row >= nrows) continue;
        float4 o;
        o.x = acc[r][0] + bv.x;
        o.y = acc[r][1] + bv.y;
        o.z = acc[r][2] + bv.z;
        o.w = acc[r][3] + bv.w;
        if constexpr (RELU) {
            o.x = fmaxf(o.x, 0.f); o.y = fmaxf(o.y, 0.f);
            o.z = fmaxf(o.z, 0.f); o.w = fmaxf(o.w, 0.f);
        }
        *reinterpret_cast<float4*>(out + (size_t)row * OUT + col) = o;
    }
}

// ---------------------------------------------------------------------------
extern "C" void kernel_launch(void* const* d_in, const int* in_sizes, int n_in,
                              void* d_out, int out_size, void* d_ws, size_t ws_size,
                              hipStream_t stream)
{
    const float* x   = (const float*)d_in[0];
    const int*   src = (const int*)d_in[1];
    const int*   dst = (const int*)d_in[2];
    const float* W1  = (const float*)d_in[3];
    const float* b1  = (const float*)d_in[4];
    const float* W2  = (const float*)d_in[5];
    const float* b2  = (const float*)d_in[6];
    float* out = (float*)d_out;

    // workspace layout (4B words), total ~42.4 MB
    float* ws  = (float*)d_ws;
    int*   wsi = (int*)d_ws;
    int*   degi     = wsi + 0;        //   50000
    float* invdeg   = ws  + 50048;    //   50000
    int*   rowStart = wsi + 100096;   //   50001
    int*   fill     = wsi + 150160;   //   50000
    int*   csr      = wsi + 200160;   //  800000
    int*   blockSum = wsi + 1000160;  //     256
    float* aggA     = ws  + 1000448;  // 6400000 (agg1 -> h in place)
    float* y2       = ws  + 7400448;  // 3200000

    hipMemsetAsync(degi, 0, NNODES * sizeof(int), stream);

    const int eb = (NEDGES + 255) / 256;
    hist_kernel<<<eb, 256, 0, stream>>>(dst, degi, NEDGES);
    partial_kernel<<<SCAN_BLOCKS, 256, 0, stream>>>(degi, blockSum, NNODES);
    finalize_kernel<<<SCAN_BLOCKS, 256, 0, stream>>>(
        degi, blockSum, SCAN_BLOCKS, rowStart, fill, invdeg, NNODES);
    permute_kernel<<<eb, 256, 0, stream>>>(src, dst, fill, csr, NEDGES);

    // layer 1: aggregate x, then in-place normalize+GEMM+bias+relu
    gather_agg_kernel<128, false><<<(NNODES + 3) / 4, 256, 0, stream>>>(
        x, csr, rowStart, nullptr, nullptr, aggA, NNODES);
    gemm_kernel<128, true, true, true><<<(NNODES + 31) / 32, 256, 0, stream>>>(
        aggA, invdeg, W1, b1, aggA, NNODES);

    // layer 2 (GEMM-first): y2 = h@W2, then aggregate+scale+bias
    gemm_kernel<64, false, false, false><<<(NNODES + 63) / 64, 256, 0, stream>>>(
        aggA, nullptr, W2, nullptr, y2, NNODES);
    gather_agg_kernel<64, true><<<(NNODES + 3) / 4, 256, 0, stream>>>(
        y2, csr, rowStart, invdeg, b2, out, NNODES);
}

// Round 4
// 219.832 us; speedup vs baseline: 12.7845x; 1.1556x over previous
//
#include <hip/hip_runtime.h>

// GCN 2-layer, CSR-gather formulation, bf16-compressed gather traffic.
//   xh   = bf16(x)
//   agg1 = gather_sum(xh)                [fp32 accum, 256B rows]
//   h    = relu((agg1*inv_deg)@W1+b1)    (fp32 GEMM, in place)
//   y2h  = bf16(h@W2)                    (fp32 GEMM, bf16 epilogue)
//   out  = gather_sum(y2h)*inv_deg + b2  [fp32 accum, 128B rows]

constexpr int NNODES = 50000;
constexpr int NEDGES = 800000;
constexpr int SCAN_BLOCKS = (NNODES + 255) / 256;  // 196 (<= 256)

typedef unsigned short ushortv8 __attribute__((ext_vector_type(8)));
typedef unsigned short ushortv4 __attribute__((ext_vector_type(4)));

static __device__ __forceinline__ unsigned short f2bf(float f) {
    unsigned u = __float_as_uint(f);
    u += 0x7fff + ((u >> 16) & 1);  // round-to-nearest-even
    return (unsigned short)(u >> 16);
}
static __device__ __forceinline__ float bf2f(unsigned short h) {
    return __uint_as_float((unsigned)h << 16);
}

// ---------------------------------------------------------------------------
__global__ __launch_bounds__(256) void hist_kernel(
    const int* __restrict__ dst, int* __restrict__ degi, int n)
{
    int i = blockIdx.x * blockDim.x + threadIdx.x;
    if (i < n) atomicAdd(&degi[dst[i]], 1);
}

__global__ __launch_bounds__(256) void partial_kernel(
    const int* __restrict__ degi, int* __restrict__ blockSum, int n)
{
    const int i = blockIdx.x * 256 + threadIdx.x;
    int v = (i < n) ? degi[i] : 0;
    #pragma unroll
    for (int off = 32; off > 0; off >>= 1) v += __shfl_down(v, off, 64);
    __shared__ int lds[4];
    if ((threadIdx.x & 63) == 0) lds[threadIdx.x >> 6] = v;
    __syncthreads();
    if (threadIdx.x == 0)
        blockSum[blockIdx.x] = lds[0] + lds[1] + lds[2] + lds[3];
}

__global__ __launch_bounds__(256) void finalize_kernel(
    const int* __restrict__ degi, const int* __restrict__ blockSum,
    int nBlocks, int* __restrict__ rowStart, int* __restrict__ fill,
    float* __restrict__ inv_deg, int n)
{
    __shared__ int lds[256];
    __shared__ int bs[256];
    const int t = threadIdx.x;
    const int i = blockIdx.x * 256 + t;
    const int d = (i < n) ? degi[i] : 0;
    lds[t] = d;
    bs[t] = (t < nBlocks) ? blockSum[t] : 0;
    __syncthreads();
    #pragma unroll
    for (int off = 1; off < 256; off <<= 1) {
        const int o = (t >= off) ? lds[t - off] : 0;
        __syncthreads();
        lds[t] += o;
        __syncthreads();
    }
    #pragma unroll
    for (int off = 1; off < 256; off <<= 1) {
        const int o = (t >= off) ? bs[t - off] : 0;
        __syncthreads();
        bs[t] += o;
        __syncthreads();
    }
    const int boff = (blockIdx.x == 0) ? 0 : bs[blockIdx.x - 1];
    if (i < n) {
        const int excl = boff + lds[t] - d;
        rowStart[i] = excl;
        fill[i] = excl;
        inv_deg[i] = 1.0f / fmaxf((float)d, 1.0f);
        if (i == n - 1) rowStart[n] = boff + lds[t];
    }
}

__global__ __launch_bounds__(256) void permute_kernel(
    const int* __restrict__ src, const int* __restrict__ dst,
    int* __restrict__ fill, int* __restrict__ csr, int n)
{
    int i = blockIdx.x * blockDim.x + threadIdx.x;
    if (i < n) {
        int slot = atomicAdd(&fill[dst[i]], 1);
        csr[slot] = src[i];
    }
}

// fp32 -> bf16 row cast, 8 elems/thread
__global__ __launch_bounds__(256) void cast_kernel(
    const float* __restrict__ in, ushortv8* __restrict__ outh, int n8)
{
    int i = blockIdx.x * 256 + threadIdx.x;
    if (i >= n8) return;
    const float4* p = reinterpret_cast<const float4*>(in) + (size_t)i * 2;
    const float4 a = p[0], b = p[1];
    ushortv8 v;
    v[0] = f2bf(a.x); v[1] = f2bf(a.y); v[2] = f2bf(a.z); v[3] = f2bf(a.w);
    v[4] = f2bf(b.x); v[5] = f2bf(b.y); v[6] = f2bf(b.z); v[7] = f2bf(b.w);
    outh[i] = v;
}

// ---------------------------------------------------------------------------
// bf16-row gather-aggregate. One wave per dst node; 64 lanes =
// EPW edge-slots x LPR 8-elem column groups (16B/lane). fp32 accumulate,
// 2-deep edge unroll for ILP, shuffle-reduce across slots, fp32 row write.
// EPI: fuse *inv_deg + bias (layer-2 tail).
// ---------------------------------------------------------------------------
template<int F, bool EPI>
__global__ __launch_bounds__(256) void gather_bf16_kernel(
    const ushortv8* __restrict__ feat, const int* __restrict__ csr,
    const int* __restrict__ rowStart, const float* __restrict__ inv_deg,
    const float* __restrict__ bias, float* __restrict__ out, int nNodes)
{
    constexpr int LPR = F / 8;     // lanes per row: 16 (F=128) / 8 (F=64)
    constexpr int EPW = 64 / LPR;  // parallel edges per wave: 4 / 8
    const int wid = (blockIdx.x * 256 + threadIdx.x) >> 6;
    if (wid >= nNodes) return;
    const int lane = threadIdx.x & 63;
    const int eslot = lane / LPR;
    const int cg = lane % LPR;     // 8-elem group index within row
    const int rs = rowStart[wid];
    const int re = rowStart[wid + 1];

    float acc0[8] = {}, acc1[8] = {};
    int j = rs + eslot;
    for (; j + EPW < re; j += 2 * EPW) {
        const int s0 = csr[j];
        const int s1 = csr[j + EPW];
        const ushortv8 v0 = feat[(size_t)s0 * LPR + cg];
        const ushortv8 v1 = feat[(size_t)s1 * LPR + cg];
        #pragma unroll
        for (int t = 0; t < 8; ++t) acc0[t] += bf2f(v0[t]);
        #pragma unroll
        for (int t = 0; t < 8; ++t) acc1[t] += bf2f(v1[t]);
    }
    if (j < re) {
        const int s0 = csr[j];
        const ushortv8 v0 = feat[(size_t)s0 * LPR + cg];
        #pragma unroll
        for (int t = 0; t < 8; ++t) acc0[t] += bf2f(v0[t]);
    }
    #pragma unroll
    for (int t = 0; t < 8; ++t) acc0[t] += acc1[t];

    #pragma unroll
    for (int off = LPR; off < 64; off <<= 1) {
        #pragma unroll
        for (int t = 0; t < 8; ++t) acc0[t] += __shfl_down(acc0[t], off, 64);
    }

    if (lane < LPR) {
        if constexpr (EPI) {
            const float s = inv_deg[wid];
            #pragma unroll
            for (int t = 0; t < 8; ++t) acc0[t] = acc0[t] * s + bias[cg * 8 + t];
        }
        float* o = out + (size_t)wid * F + cg * 8;
        *reinterpret_cast<float4*>(o) =
            make_float4(acc0[0], acc0[1], acc0[2], acc0[3]);
        *reinterpret_cast<float4*>(o + 4) =
            make_float4(acc0[4], acc0[5], acc0[6], acc0[7]);
    }
}

// ---------------------------------------------------------------------------
// fp32 GEMM, K=128, 4x4 register tile, A staged in LDS (+4 pad).
// SCALE: A rows * inv_deg at staging. BIAS/RELU epilogue. OBF16: emit bf16.
// Safe in-place for fp32 out (blocks own disjoint rows, staged to LDS first).
// ---------------------------------------------------------------------------
template<int OUT, bool SCALE, bool BIAS, bool RELU, bool OBF16>
__global__ __launch_bounds__(256) void gemm_kernel(
    const float* __restrict__ A, const float* __restrict__ inv_deg,
    const float* __restrict__ W, const float* __restrict__ bias,
    void* __restrict__ outv, int nrows)
{
    constexpr int CG = OUT / 4;
    constexpr int RGROUPS = 256 / CG;
    constexpr int ROWS = RGROUPS * 4;
    constexpr int LDK = 132;
    __shared__ float lds_a[ROWS][LDK];

    const int row0 = blockIdx.x * ROWS;
    const int col = (threadIdx.x % CG) * 4;
    const int rbase = (threadIdx.x / CG) * 4;

    for (int i = threadIdx.x * 4; i < ROWS * 128; i += 256 * 4) {
        const int r = i >> 7;
        const int k = i & 127;
        const int row = row0 + r;
        float4 v = make_float4(0.f, 0.f, 0.f, 0.f);
        if (row < nrows) {
            v = *reinterpret_cast<const float4*>(A + (size_t)row * 128 + k);
            if constexpr (SCALE) {
                const float s = inv_deg[row];
                v.x *= s; v.y *= s; v.z *= s; v.w *= s;
            }
        }
        *reinterpret_cast<float4*>(&lds_a[r][k]) = v;
    }
    __syncthreads();

    float acc[4][4] = {};
    #pragma unroll 4
    for (int k = 0; k < 128; ++k) {
        const float4 w = *reinterpret_cast<const float4*>(W + k * OUT + col);
        #pragma unroll
        for (int r = 0; r < 4; ++r) {
            const float a = lds_a[rbase + r][k];
            acc[r][0] += a * w.x;
            acc[r][1] += a * w.y;
            acc[r][2] += a * w.z;
            acc[r][3] += a * w.w;
        }
    }

    float4 bv = make_float4(0.f, 0.f, 0.f, 0.f);
    if constexpr (BIAS) bv = *reinterpret_cast<const float4*>(bias + col);
    #pragma unroll
    for (int r = 0; r < 4; ++r) {
        const int row = row0 + rbase + r;
        if (row >= nrows) continue;
        float4 o;
        o.x = acc[r][0] + bv.x;
        o.y = acc[r][1] + bv.y;
        o.z = acc[r][2] + bv.z;
        o.w = acc[r][3] + bv.w;
        if constexpr (RELU) {
            o.x = fmaxf(o.x, 0.f); o.y = fmaxf(o.y, 0.f);
            o.z = fmaxf(o.z, 0.f); o.w = fmaxf(o.w, 0.f);
        }
        if constexpr (OBF16) {
            ushortv4 ov;
            ov[0] = f2bf(o.x); ov[1] = f2bf(o.y);
            ov[2] = f2bf(o.z); ov[3] = f2bf(o.w);
            *reinterpret_cast<ushortv4*>(
                (unsigned short*)outv + (size_t)row * OUT + col) = ov;
        } else {
            *reinterpret_cast<float4*>(
                (float*)outv + (size_t)row * OUT + col) = o;
        }
    }
}

// ---------------------------------------------------------------------------
extern "C" void kernel_launch(void* const* d_in, const int* in_sizes, int n_in,
                              void* d_out, int out_size, void* d_ws, size_t ws_size,
                              hipStream_t stream)
{
    const float* x   = (const float*)d_in[0];
    const int*   src = (const int*)d_in[1];
    const int*   dst = (const int*)d_in[2];
    const float* W1  = (const float*)d_in[3];
    const float* b1  = (const float*)d_in[4];
    const float* W2  = (const float*)d_in[5];
    const float* b2  = (const float*)d_in[6];
    float* out = (float*)d_out;

    // workspace layout (4B word offsets), total ~48.8 MB
    float* ws  = (float*)d_ws;
    int*   wsi = (int*)d_ws;
    int*       degi     = wsi + 0;         //   50000
    float*     invdeg   = ws  + 50048;     //   50000
    int*       rowStart = wsi + 100096;    //   50001
    int*       fill     = wsi + 150160;    //   50000
    int*       csr      = wsi + 200160;    //  800000
    int*       blockSum = wsi + 1000160;   //     256
    ushortv8*  xh       = (ushortv8*)(wsi + 1000448);   // 50000x128 bf16
    float*     aggA     = ws  + 4200448;   // 6400000 (agg1 -> h in place)
    ushortv8*  y2h      = (ushortv8*)(wsi + 10600448);  // 50000x64 bf16

    hipMemsetAsync(degi, 0, NNODES * sizeof(int), stream);

    const int eb = (NEDGES + 255) / 256;
    hist_kernel<<<eb, 256, 0, stream>>>(dst, degi, NEDGES);
    partial_kernel<<<SCAN_BLOCKS, 256, 0, stream>>>(degi, blockSum, NNODES);
    finalize_kernel<<<SCAN_BLOCKS, 256, 0, stream>>>(
        degi, blockSum, SCAN_BLOCKS, rowStart, fill, invdeg, NNODES);
    permute_kernel<<<eb, 256, 0, stream>>>(src, dst, fill, csr, NEDGES);

    // bf16 feature staging
    cast_kernel<<<(NNODES * 128 / 8 + 255) / 256, 256, 0, stream>>>(
        x, xh, NNODES * 128 / 8);

    // layer 1: aggregate xh, then in-place normalize+GEMM+bias+relu (fp32)
    gather_bf16_kernel<128, false><<<(NNODES + 3) / 4, 256, 0, stream>>>(
        xh, csr, rowStart, nullptr, nullptr, aggA, NNODES);
    gemm_kernel<128, true, true, true, false>
        <<<(NNODES + 31) / 32, 256, 0, stream>>>(
        aggA, invdeg, W1, b1, aggA, NNODES);

    // layer 2 (GEMM-first): y2h = bf16(h@W2), then aggregate+scale+bias
    gemm_kernel<64, false, false, false, true>
        <<<(NNODES + 63) / 64, 256, 0, stream>>>(
        aggA, nullptr, W2, nullptr, y2h, NNODES);
    gather_bf16_kernel<64, true><<<(NNODES + 3) / 4, 256, 0, stream>>>(
        y2h, csr, rowStart, invdeg, b2, out, NNODES);
}

// Round 7
// 197.137 us; speedup vs baseline: 14.2563x; 1.1151x over previous
//
#include <hip/hip_runtime.h>

// GCN 2-layer, CSR-gather formulation, bf16-compressed gather traffic.
// CSR build via deterministic 2-phase partition (bucket = dst>>8, 196 buckets):
//   partA: per-WG LDS hist + scan -> scatter packed edges into WG-private
//          tmp region [w*PER,..); store per-(WG,bucket) counts H / offsets LOFS
//   partB: per-bucket: scan H column -> binary-search merge of 200 runs ->
//          LDS-fill scatter into the bucket's contiguous csr window
//   xh   = bf16(x)
//   agg1 = gather_sum(xh)                [fp32 accum, 256B rows]
//   h    = relu((agg1*inv_deg)@W1+b1)    (fp32 GEMM, in place)
//   y2h  = bf16(h@W2)                    (fp32 GEMM, bf16 epilogue)
//   out  = gather_sum(y2h)*inv_deg + b2  [fp32 accum, 128B rows]
//
// NOTE r5/r6 failed with NaN because aggA was placed at xh+1.6M words (y2h's
// size) instead of xh+3.2M -> gather1's fp32 writes clobbered xh rows >=25000.
// Layout below is cumulative; every offset = previous offset + previous size.

constexpr int NNODES = 50000;
constexpr int NEDGES = 800000;
constexpr int SCAN_BLOCKS = (NNODES + 255) / 256;     // 196 == bucket count
constexpr int ABLOCKS = 200;                          // partA workgroups
constexpr int PER = (NEDGES + ABLOCKS - 1) / ABLOCKS; // 4000 edges per WG

typedef unsigned short ushortv8 __attribute__((ext_vector_type(8)));
typedef unsigned short ushortv4 __attribute__((ext_vector_type(4)));

static __device__ __forceinline__ unsigned short f2bf(float f) {
    unsigned u = __float_as_uint(f);
    u += 0x7fff + ((u >> 16) & 1);  // round-to-nearest-even
    return (unsigned short)(u >> 16);
}
static __device__ __forceinline__ float bf2f(unsigned short h) {
    return __uint_as_float((unsigned)h << 16);
}

// ---------------------------------------------------------------------------
__global__ __launch_bounds__(256) void hist_kernel(
    const int* __restrict__ dst, int* __restrict__ degi, int n)
{
    int i = blockIdx.x * blockDim.x + threadIdx.x;
    if (i < n) atomicAdd(&degi[dst[i]], 1);
}

__global__ __launch_bounds__(256) void partial_kernel(
    const int* __restrict__ degi, int* __restrict__ blockSum, int n)
{
    const int i = blockIdx.x * 256 + threadIdx.x;
    int v = (i < n) ? degi[i] : 0;
    #pragma unroll
    for (int off = 32; off > 0; off >>= 1) v += __shfl_down(v, off, 64);
    __shared__ int lds[4];
    if ((threadIdx.x & 63) == 0) lds[threadIdx.x >> 6] = v;
    __syncthreads();
    if (threadIdx.x == 0)
        blockSum[blockIdx.x] = lds[0] + lds[1] + lds[2] + lds[3];
}

__global__ __launch_bounds__(256) void finalize_kernel(
    const int* __restrict__ degi, const int* __restrict__ blockSum,
    int nBlocks, int* __restrict__ rowStart, float* __restrict__ inv_deg, int n)
{
    __shared__ int lds[256];
    __shared__ int bs[256];
    const int t = threadIdx.x;
    const int i = blockIdx.x * 256 + t;
    const int d = (i < n) ? degi[i] : 0;
    lds[t] = d;
    bs[t] = (t < nBlocks) ? blockSum[t] : 0;
    __syncthreads();
    #pragma unroll
    for (int off = 1; off < 256; off <<= 1) {
        const int o = (t >= off) ? lds[t - off] : 0;
        __syncthreads();
        lds[t] += o;
        __syncthreads();
    }
    #pragma unroll
    for (int off = 1; off < 256; off <<= 1) {
        const int o = (t >= off) ? bs[t - off] : 0;
        __syncthreads();
        bs[t] += o;
        __syncthreads();
    }
    const int boff = (blockIdx.x == 0) ? 0 : bs[blockIdx.x - 1];
    if (i < n) {
        const int excl = boff + lds[t] - d;
        rowStart[i] = excl;
        inv_deg[i] = 1.0f / fmaxf((float)d, 1.0f);
        if (i == n - 1) rowStart[n] = boff + lds[t];
    }
}

// ---------------------------------------------------------------------------
// partA: deterministic per-WG bucket partition. WG w owns edges
// [w*PER, w*PER+chunk); scatters packed (src<<8 | dst&255) into its OWN tmp
// region grouped by bucket, via LDS hist + exclusive scan + LDS cursors.
// Stores H[w][b] (count) and LOFS[w][b] (intra-region offset).
// ---------------------------------------------------------------------------
__global__ __launch_bounds__(256) void partA_kernel(
    const int* __restrict__ src, const int* __restrict__ dst,
    unsigned* __restrict__ tmp, int* __restrict__ H,
    int* __restrict__ LOFS, int nE)
{
    __shared__ int cnt[256];
    __shared__ int ofs[256];
    __shared__ int cur[256];
    const int t = threadIdx.x;
    cnt[t] = 0;
    __syncthreads();
    const int lo = blockIdx.x * PER;
    const int hi = min(lo + PER, nE);
    for (int i = lo + t; i < hi; i += 256)
        atomicAdd(&cnt[dst[i] >> 8], 1);
    __syncthreads();
    ofs[t] = cnt[t];
    __syncthreads();
    #pragma unroll
    for (int off = 1; off < 256; off <<= 1) {
        const int o = (t >= off) ? ofs[t - off] : 0;
        __syncthreads();
        ofs[t] += o;
        __syncthreads();
    }
    const int excl = ofs[t] - cnt[t];  // exclusive offset within this region
    cur[t] = excl;
    H[blockIdx.x * 256 + t] = cnt[t];
    LOFS[blockIdx.x * 256 + t] = excl;
    __syncthreads();
    for (int i = lo + t; i < hi; i += 256) {
        const int d = dst[i];
        const unsigned pk = ((unsigned)src[i] << 8) | (unsigned)(d & 255);
        const int pos = lo + atomicAdd(&cur[d >> 8], 1);
        tmp[pos] = pk;
    }
}

// ---------------------------------------------------------------------------
// partB: one WG per bucket. Load H/LOFS column b, scan run lengths, then
// binary-search merge over the 200 runs; scatter src into the bucket's
// contiguous csr window with LDS fill counters seeded from rowStart.
// ---------------------------------------------------------------------------
__global__ __launch_bounds__(256) void partB_kernel(
    const unsigned* __restrict__ tmp, const int* __restrict__ H,
    const int* __restrict__ LOFS, const int* __restrict__ rowStart,
    int* __restrict__ csr, int nNodes)
{
    __shared__ int fill[256];
    __shared__ int pfx[ABLOCKS + 1];
    __shared__ int base[ABLOCKS];
    const int b = blockIdx.x;
    const int t = threadIdx.x;
    const int node = b * 256 + t;
    fill[t] = (node < nNodes) ? rowStart[node] : 0;
    if (t < ABLOCKS) {
        pfx[t + 1] = H[t * 256 + b];
        base[t] = t * PER + LOFS[t * 256 + b];
    }
    if (t == 0) pfx[0] = 0;
    __syncthreads();
    if (t == 0) {
        int run = 0;
        for (int w = 0; w < ABLOCKS; ++w) { run += pfx[w + 1]; pfx[w + 1] = run; }
    }
    __syncthreads();
    const int total = pfx[ABLOCKS];  // == edges in this bucket
    for (int j = t; j < total; j += 256) {
        int loW = 0, hiW = ABLOCKS;          // largest w with pfx[w] <= j
        while (hiW - loW > 1) {
            const int mid = (loW + hiW) >> 1;
            if (pfx[mid] <= j) loW = mid; else hiW = mid;
        }
        const unsigned p = tmp[base[loW] + (j - pfx[loW])];
        const int pos = atomicAdd(&fill[p & 255u], 1);
        csr[pos] = (int)(p >> 8);
    }
}

// fp32 -> bf16 row cast, 8 elems/thread
__global__ __launch_bounds__(256) void cast_kernel(
    const float* __restrict__ in, ushortv8* __restrict__ outh, int n8)
{
    int i = blockIdx.x * 256 + threadIdx.x;
    if (i >= n8) return;
    const float4* p = reinterpret_cast<const float4*>(in) + (size_t)i * 2;
    const float4 a = p[0], b = p[1];
    ushortv8 v;
    v[0] = f2bf(a.x); v[1] = f2bf(a.y); v[2] = f2bf(a.z); v[3] = f2bf(a.w);
    v[4] = f2bf(b.x); v[5] = f2bf(b.y); v[6] = f2bf(b.z); v[7] = f2bf(b.w);
    outh[i] = v;
}

// ---------------------------------------------------------------------------
// bf16-row gather-aggregate. One wave per dst node; 64 lanes =
// EPW edge-slots x LPR 8-elem column groups (16B/lane). fp32 accumulate,
// 2-deep edge unroll, shuffle-reduce across slots, fp32 row write.
// EPI: fuse *inv_deg + bias (layer-2 tail).
// ---------------------------------------------------------------------------
template<int F, bool EPI>
__global__ __launch_bounds__(256) void gather_bf16_kernel(
    const ushortv8* __restrict__ feat, const int* __restrict__ csr,
    const int* __restrict__ rowStart, const float* __restrict__ inv_deg,
    const float* __restrict__ bias, float* __restrict__ out, int nNodes)
{
    constexpr int LPR = F / 8;     // lanes per row: 16 (F=128) / 8 (F=64)
    constexpr int EPW = 64 / LPR;  // parallel edges per wave: 4 / 8
    const int wid = (blockIdx.x * 256 + threadIdx.x) >> 6;
    if (wid >= nNodes) return;
    const int lane = threadIdx.x & 63;
    const int eslot = lane / LPR;
    const int cg = lane % LPR;
    const int rs = rowStart[wid];
    const int re = rowStart[wid + 1];

    float acc0[8] = {}, acc1[8] = {};
    int j = rs + eslot;
    for (; j + EPW < re; j += 2 * EPW) {
        const int s0 = csr[j];
        const int s1 = csr[j + EPW];
        const ushortv8 v0 = feat[(size_t)s0 * LPR + cg];
        const ushortv8 v1 = feat[(size_t)s1 * LPR + cg];
        #pragma unroll
        for (int t = 0; t < 8; ++t) acc0[t] += bf2f(v0[t]);
        #pragma unroll
        for (int t = 0; t < 8; ++t) acc1[t] += bf2f(v1[t]);
    }
    if (j < re) {
        const int s0 = csr[j];
        const ushortv8 v0 = feat[(size_t)s0 * LPR + cg];
        #pragma unroll
        for (int t = 0; t < 8; ++t) acc0[t] += bf2f(v0[t]);
    }
    #pragma unroll
    for (int t = 0; t < 8; ++t) acc0[t] += acc1[t];

    #pragma unroll
    for (int off = LPR; off < 64; off <<= 1) {
        #pragma unroll
        for (int t = 0; t < 8; ++t) acc0[t] += __shfl_down(acc0[t], off, 64);
    }

    if (lane < LPR) {
        if constexpr (EPI) {
            const float s = inv_deg[wid];
            #pragma unroll
            for (int t = 0; t < 8; ++t) acc0[t] = acc0[t] * s + bias[cg * 8 + t];
        }
        float* o = out + (size_t)wid * F + cg * 8;
        *reinterpret_cast<float4*>(o) =
            make_float4(acc0[0], acc0[1], acc0[2], acc0[3]);
        *reinterpret_cast<float4*>(o + 4) =
            make_float4(acc0[4], acc0[5], acc0[6], acc0[7]);
    }
}

// ---------------------------------------------------------------------------
// fp32 GEMM, K=128, 4x4 register tile, A staged in LDS (+4 pad).
// SCALE: A rows * inv_deg at staging. BIAS/RELU epilogue. OBF16: emit bf16.
// Safe in-place for fp32 out (blocks own disjoint rows, staged to LDS first).
// ---------------------------------------------------------------------------
template<int OUT, bool SCALE, bool BIAS, bool RELU, bool OBF16>
__global__ __launch_bounds__(256) void gemm_kernel(
    const float* __restrict__ A, const float* __restrict__ inv_deg,
    const float* __restrict__ W, const float* __restrict__ bias,
    void* __restrict__ outv, int nrows)
{
    constexpr int CG = OUT / 4;
    constexpr int RGROUPS = 256 / CG;
    constexpr int ROWS = RGROUPS * 4;
    constexpr int LDK = 132;
    __shared__ float lds_a[ROWS][LDK];

    const int row0 = blockIdx.x * ROWS;
    const int col = (threadIdx.x % CG) * 4;
    const int rbase = (threadIdx.x / CG) * 4;

    for (int i = threadIdx.x * 4; i < ROWS * 128; i += 256 * 4) {
        const int r = i >> 7;
        const int k = i & 127;
        const int row = row0 + r;
        float4 v = make_float4(0.f, 0.f, 0.f, 0.f);
        if (row < nrows) {
            v = *reinterpret_cast<const float4*>(A + (size_t)row * 128 + k);
            if constexpr (SCALE) {
                const float s = inv_deg[row];
                v.x *= s; v.y *= s; v.z *= s; v.w *= s;
            }
        }
        *reinterpret_cast<float4*>(&lds_a[r][k]) = v;
    }
    __syncthreads();

    float acc[4][4] = {};
    #pragma unroll 4
    for (int k = 0; k < 128; ++k) {
        const float4 w = *reinterpret_cast<const float4*>(W + k * OUT + col);
        #pragma unroll
        for (int r = 0; r < 4; ++r) {
            const float a = lds_a[rbase + r][k];
            acc[r][0] += a * w.x;
            acc[r][1] += a * w.y;
            acc[r][2] += a * w.z;
            acc[r][3] += a * w.w;
        }
    }

    float4 bv = make_float4(0.f, 0.f, 0.f, 0.f);
    if constexpr (BIAS) bv = *reinterpret_cast<const float4*>(bias + col);
    #pragma unroll
    for (int r = 0; r < 4; ++r) {
        const int row = row0 + rbase + r;
        if (row >= nrows) continue;
        float4 o;
        o.x = acc[r][0] + bv.x;
        o.y = acc[r][1] + bv.y;
        o.z = acc[r][2] + bv.z;
        o.w = acc[r][3] + bv.w;
        if constexpr (RELU) {
            o.x = fmaxf(o.x, 0.f); o.y = fmaxf(o.y, 0.f);
            o.z = fmaxf(o.z, 0.f); o.w = fmaxf(o.w, 0.f);
        }
        if constexpr (OBF16) {
            ushortv4 ov;
            ov[0] = f2bf(o.x); ov[1] = f2bf(o.y);
            ov[2] = f2bf(o.z); ov[3] = f2bf(o.w);
            *reinterpret_cast<ushortv4*>(
                (unsigned short*)outv + (size_t)row * OUT + col) = ov;
        } else {
            *reinterpret_cast<float4*>(
                (float*)outv + (size_t)row * OUT + col) = o;
        }
    }
}

// ---------------------------------------------------------------------------
extern "C" void kernel_launch(void* const* d_in, const int* in_sizes, int n_in,
                              void* d_out, int out_size, void* d_ws, size_t ws_size,
                              hipStream_t stream)
{
    const float* x   = (const float*)d_in[0];
    const int*   src = (const int*)d_in[1];
    const int*   dst = (const int*)d_in[2];
    const float* W1  = (const float*)d_in[3];
    const float* b1  = (const float*)d_in[4];
    const float* W2  = (const float*)d_in[5];
    const float* b2  = (const float*)d_in[6];
    float* out = (float*)d_out;

    // Cumulative workspace layout (4B word offsets). offset_k = offset_{k-1} + size_{k-1}.
    //   name      offset      size (words)
    //   degi      0           50048
    //   invdeg    50048       50048
    //   rowStart  100096      50048   (needs 50001)
    //   blockSum  150144      256
    //   H         150400      51200   (200*256)
    //   LOFS      201600      51200
    //   csr       252800      800000
    //   tmp       1052800     800000
    //   xh        1852800     3200000 (50000*128 bf16 = 3.2M words; y2h aliases
    //                                  its first 1600000 words after gather1)
    //   aggA      5052800     6400000
    //   total     11452800 words = 45.8 MB
    float* ws  = (float*)d_ws;
    int*   wsi = (int*)d_ws;
    int*       degi     = wsi + 0;
    float*     invdeg   = ws  + 50048;
    int*       rowStart = wsi + 100096;
    int*       blockSum = wsi + 150144;
    int*       H        = wsi + 150400;
    int*       LOFS     = wsi + 201600;
    int*       csr      = wsi + 252800;
    unsigned*  tmp      = (unsigned*)(wsi + 1052800);
    ushortv8*  xh       = (ushortv8*)(wsi + 1852800);
    ushortv8*  y2h      = (ushortv8*)(wsi + 1852800);  // alias: xh dead after gather1
    float*     aggA     = ws  + 5052800;

    hipMemsetAsync(degi, 0, NNODES * sizeof(int), stream);

    const int eb = (NEDGES + 255) / 256;
    hist_kernel<<<eb, 256, 0, stream>>>(dst, degi, NEDGES);
    partial_kernel<<<SCAN_BLOCKS, 256, 0, stream>>>(degi, blockSum, NNODES);
    finalize_kernel<<<SCAN_BLOCKS, 256, 0, stream>>>(
        degi, blockSum, SCAN_BLOCKS, rowStart, invdeg, NNODES);
    partA_kernel<<<ABLOCKS, 256, 0, stream>>>(src, dst, tmp, H, LOFS, NEDGES);
    partB_kernel<<<SCAN_BLOCKS, 256, 0, stream>>>(
        tmp, H, LOFS, rowStart, csr, NNODES);

    // bf16 feature staging
    cast_kernel<<<(NNODES * 128 / 8 + 255) / 256, 256, 0, stream>>>(
        x, xh, NNODES * 128 / 8);

    // layer 1: aggregate xh, then in-place normalize+GEMM+bias+relu (fp32)
    gather_bf16_kernel<128, false><<<(NNODES + 3) / 4, 256, 0, stream>>>(
        xh, csr, rowStart, nullptr, nullptr, aggA, NNODES);
    gemm_kernel<128, true, true, true, false>
        <<<(NNODES + 31) / 32, 256, 0, stream>>>(
        aggA, invdeg, W1, b1, aggA, NNODES);

    // layer 2 (GEMM-first): y2h = bf16(h@W2), then aggregate+scale+bias
    // (y2h aliases xh — xh is dead after gather1 above)
    gemm_kernel<64, false, false, false, true>
        <<<(NNODES + 63) / 64, 256, 0, stream>>>(
        aggA, nullptr, W2, nullptr, y2h, NNODES);
    gather_bf16_kernel<64, true><<<(NNODES + 3) / 4, 256, 0, stream>>>(
        y2h, csr, rowStart, invdeg, b2, out, NNODES);
}

// Round 8
// 197.125 us; speedup vs baseline: 14.2571x; 1.0001x over previous
//
#include <hip/hip_runtime.h>

// GCN 2-layer, CSR-gather formulation, bf16-compressed gather traffic.
// CSR build via deterministic 2-phase partition (bucket = dst>>8, 196 buckets):
//   partA: per-WG LDS hist + scan -> scatter packed edges into WG-private
//          tmp region [w*PER,..); store per-(WG,bucket) counts H / offsets LOFS
//   partB: per-bucket: scan H column -> binary-search merge of 200 runs ->
//          LDS-fill scatter into the bucket's contiguous csr window
//   xh   = bf16(x)
//   agg1 = gather_sum(xh)                [fp32 accum, 256B rows]
//   h    = relu((agg1*inv_deg)@W1+b1)    (fp32 GEMM, in place)
//   y2h  = bf16(h@W2)                    (fp32 GEMM, bf16 epilogue)
//   out  = gather_sum(y2h)*inv_deg + b2  [fp32 accum, 128B rows]
//
// r8: replaced hipMemsetAsync(degi) with zero_kernel — rocclr fillBuffer was
// 42us/replay (21% of runtime) for a 200KB fill.

constexpr int NNODES = 50000;
constexpr int NEDGES = 800000;
constexpr int SCAN_BLOCKS = (NNODES + 255) / 256;     // 196 == bucket count
constexpr int ABLOCKS = 200;                          // partA workgroups
constexpr int PER = (NEDGES + ABLOCKS - 1) / ABLOCKS; // 4000 edges per WG

typedef unsigned short ushortv8 __attribute__((ext_vector_type(8)));
typedef unsigned short ushortv4 __attribute__((ext_vector_type(4)));

static __device__ __forceinline__ unsigned short f2bf(float f) {
    unsigned u = __float_as_uint(f);
    u += 0x7fff + ((u >> 16) & 1);  // round-to-nearest-even
    return (unsigned short)(u >> 16);
}
static __device__ __forceinline__ float bf2f(unsigned short h) {
    return __uint_as_float((unsigned)h << 16);
}

// ---------------------------------------------------------------------------
__global__ __launch_bounds__(256) void zero_kernel(int* __restrict__ p, int n)
{
    const int i = blockIdx.x * 256 + threadIdx.x;
    if (i < n) p[i] = 0;
}

__global__ __launch_bounds__(256) void hist_kernel(
    const int* __restrict__ dst, int* __restrict__ degi, int n)
{
    int i = blockIdx.x * blockDim.x + threadIdx.x;
    if (i < n) atomicAdd(&degi[dst[i]], 1);
}

__global__ __launch_bounds__(256) void partial_kernel(
    const int* __restrict__ degi, int* __restrict__ blockSum, int n)
{
    const int i = blockIdx.x * 256 + threadIdx.x;
    int v = (i < n) ? degi[i] : 0;
    #pragma unroll
    for (int off = 32; off > 0; off >>= 1) v += __shfl_down(v, off, 64);
    __shared__ int lds[4];
    if ((threadIdx.x & 63) == 0) lds[threadIdx.x >> 6] = v;
    __syncthreads();
    if (threadIdx.x == 0)
        blockSum[blockIdx.x] = lds[0] + lds[1] + lds[2] + lds[3];
}

__global__ __launch_bounds__(256) void finalize_kernel(
    const int* __restrict__ degi, const int* __restrict__ blockSum,
    int nBlocks, int* __restrict__ rowStart, float* __restrict__ inv_deg, int n)
{
    __shared__ int lds[256];
    __shared__ int bs[256];
    const int t = threadIdx.x;
    const int i = blockIdx.x * 256 + t;
    const int d = (i < n) ? degi[i] : 0;
    lds[t] = d;
    bs[t] = (t < nBlocks) ? blockSum[t] : 0;
    __syncthreads();
    #pragma unroll
    for (int off = 1; off < 256; off <<= 1) {
        const int o = (t >= off) ? lds[t - off] : 0;
        __syncthreads();
        lds[t] += o;
        __syncthreads();
    }
    #pragma unroll
    for (int off = 1; off < 256; off <<= 1) {
        const int o = (t >= off) ? bs[t - off] : 0;
        __syncthreads();
        bs[t] += o;
        __syncthreads();
    }
    const int boff = (blockIdx.x == 0) ? 0 : bs[blockIdx.x - 1];
    if (i < n) {
        const int excl = boff + lds[t] - d;
        rowStart[i] = excl;
        inv_deg[i] = 1.0f / fmaxf((float)d, 1.0f);
        if (i == n - 1) rowStart[n] = boff + lds[t];
    }
}

// ---------------------------------------------------------------------------
// partA: deterministic per-WG bucket partition. WG w owns edges
// [w*PER, w*PER+chunk); scatters packed (src<<8 | dst&255) into its OWN tmp
// region grouped by bucket, via LDS hist + exclusive scan + LDS cursors.
// Stores H[w][b] (count) and LOFS[w][b] (intra-region offset).
// ---------------------------------------------------------------------------
__global__ __launch_bounds__(256) void partA_kernel(
    const int* __restrict__ src, const int* __restrict__ dst,
    unsigned* __restrict__ tmp, int* __restrict__ H,
    int* __restrict__ LOFS, int nE)
{
    __shared__ int cnt[256];
    __shared__ int ofs[256];
    __shared__ int cur[256];
    const int t = threadIdx.x;
    cnt[t] = 0;
    __syncthreads();
    const int lo = blockIdx.x * PER;
    const int hi = min(lo + PER, nE);
    for (int i = lo + t; i < hi; i += 256)
        atomicAdd(&cnt[dst[i] >> 8], 1);
    __syncthreads();
    ofs[t] = cnt[t];
    __syncthreads();
    #pragma unroll
    for (int off = 1; off < 256; off <<= 1) {
        const int o = (t >= off) ? ofs[t - off] : 0;
        __syncthreads();
        ofs[t] += o;
        __syncthreads();
    }
    const int excl = ofs[t] - cnt[t];  // exclusive offset within this region
    cur[t] = excl;
    H[blockIdx.x * 256 + t] = cnt[t];
    LOFS[blockIdx.x * 256 + t] = excl;
    __syncthreads();
    for (int i = lo + t; i < hi; i += 256) {
        const int d = dst[i];
        const unsigned pk = ((unsigned)src[i] << 8) | (unsigned)(d & 255);
        const int pos = lo + atomicAdd(&cur[d >> 8], 1);
        tmp[pos] = pk;
    }
}

// ---------------------------------------------------------------------------
// partB: one WG per bucket. Load H/LOFS column b, scan run lengths, then
// binary-search merge over the 200 runs; scatter src into the bucket's
// contiguous csr window with LDS fill counters seeded from rowStart.
// ---------------------------------------------------------------------------
__global__ __launch_bounds__(256) void partB_kernel(
    const unsigned* __restrict__ tmp, const int* __restrict__ H,
    const int* __restrict__ LOFS, const int* __restrict__ rowStart,
    int* __restrict__ csr, int nNodes)
{
    __shared__ int fill[256];
    __shared__ int pfx[ABLOCKS + 1];
    __shared__ int base[ABLOCKS];
    const int b = blockIdx.x;
    const int t = threadIdx.x;
    const int node = b * 256 + t;
    fill[t] = (node < nNodes) ? rowStart[node] : 0;
    if (t < ABLOCKS) {
        pfx[t + 1] = H[t * 256 + b];
        base[t] = t * PER + LOFS[t * 256 + b];
    }
    if (t == 0) pfx[0] = 0;
    __syncthreads();
    if (t == 0) {
        int run = 0;
        for (int w = 0; w < ABLOCKS; ++w) { run += pfx[w + 1]; pfx[w + 1] = run; }
    }
    __syncthreads();
    const int total = pfx[ABLOCKS];  // == edges in this bucket
    for (int j = t; j < total; j += 256) {
        int loW = 0, hiW = ABLOCKS;          // largest w with pfx[w] <= j
        while (hiW - loW > 1) {
            const int mid = (loW + hiW) >> 1;
            if (pfx[mid] <= j) loW = mid; else hiW = mid;
        }
        const unsigned p = tmp[base[loW] + (j - pfx[loW])];
        const int pos = atomicAdd(&fill[p & 255u], 1);
        csr[pos] = (int)(p >> 8);
    }
}

// fp32 -> bf16 row cast, 8 elems/thread
__global__ __launch_bounds__(256) void cast_kernel(
    const float* __restrict__ in, ushortv8* __restrict__ outh, int n8)
{
    int i = blockIdx.x * 256 + threadIdx.x;
    if (i >= n8) return;
    const float4* p = reinterpret_cast<const float4*>(in) + (size_t)i * 2;
    const float4 a = p[0], b = p[1];
    ushortv8 v;
    v[0] = f2bf(a.x); v[1] = f2bf(a.y); v[2] = f2bf(a.z); v[3] = f2bf(a.w);
    v[4] = f2bf(b.x); v[5] = f2bf(b.y); v[6] = f2bf(b.z); v[7] = f2bf(b.w);
    outh[i] = v;
}

// ---------------------------------------------------------------------------
// bf16-row gather-aggregate. One wave per dst node; 64 lanes =
// EPW edge-slots x LPR 8-elem column groups (16B/lane). fp32 accumulate,
// 2-deep edge unroll, shuffle-reduce across slots, fp32 row write.
// EPI: fuse *inv_deg + bias (layer-2 tail).
// ---------------------------------------------------------------------------
template<int F, bool EPI>
__global__ __launch_bounds__(256) void gather_bf16_kernel(
    const ushortv8* __restrict__ feat, const int* __restrict__ csr,
    const int* __restrict__ rowStart, const float* __restrict__ inv_deg,
    const float* __restrict__ bias, float* __restrict__ out, int nNodes)
{
    constexpr int LPR = F / 8;     // lanes per row: 16 (F=128) / 8 (F=64)
    constexpr int EPW = 64 / LPR;  // parallel edges per wave: 4 / 8
    const int wid = (blockIdx.x * 256 + threadIdx.x) >> 6;
    if (wid >= nNodes) return;
    const int lane = threadIdx.x & 63;
    const int eslot = lane / LPR;
    const int cg = lane % LPR;
    const int rs = rowStart[wid];
    const int re = rowStart[wid + 1];

    float acc0[8] = {}, acc1[8] = {};
    int j = rs + eslot;
    for (; j + EPW < re; j += 2 * EPW) {
        const int s0 = csr[j];
        const int s1 = csr[j + EPW];
        const ushortv8 v0 = feat[(size_t)s0 * LPR + cg];
        const ushortv8 v1 = feat[(size_t)s1 * LPR + cg];
        #pragma unroll
        for (int t = 0; t < 8; ++t) acc0[t] += bf2f(v0[t]);
        #pragma unroll
        for (int t = 0; t < 8; ++t) acc1[t] += bf2f(v1[t]);
    }
    if (j < re) {
        const int s0 = csr[j];
        const ushortv8 v0 = feat[(size_t)s0 * LPR + cg];
        #pragma unroll
        for (int t = 0; t < 8; ++t) acc0[t] += bf2f(v0[t]);
    }
    #pragma unroll
    for (int t = 0; t < 8; ++t) acc0[t] += acc1[t];

    #pragma unroll
    for (int off = LPR; off < 64; off <<= 1) {
        #pragma unroll
        for (int t = 0; t < 8; ++t) acc0[t] += __shfl_down(acc0[t], off, 64);
    }

    if (lane < LPR) {
        if constexpr (EPI) {
            const float s = inv_deg[wid];
            #pragma unroll
            for (int t = 0; t < 8; ++t) acc0[t] = acc0[t] * s + bias[cg * 8 + t];
        }
        float* o = out + (size_t)wid * F + cg * 8;
        *reinterpret_cast<float4*>(o) =
            make_float4(acc0[0], acc0[1], acc0[2], acc0[3]);
        *reinterpret_cast<float4*>(o + 4) =
            make_float4(acc0[4], acc0[5], acc0[6], acc0[7]);
    }
}

// ---------------------------------------------------------------------------
// fp32 GEMM, K=128, 4x4 register tile, A staged in LDS (+4 pad).
// SCALE: A rows * inv_deg at staging. BIAS/RELU epilogue. OBF16: emit bf16.
// Safe in-place for fp32 out (blocks own disjoint rows, staged to LDS first).
// ---------------------------------------------------------------------------
template<int OUT, bool SCALE, bool BIAS, bool RELU, bool OBF16>
__global__ __launch_bounds__(256) void gemm_kernel(
    const float* __restrict__ A, const float* __restrict__ inv_deg,
    const float* __restrict__ W, const float* __restrict__ bias,
    void* __restrict__ outv, int nrows)
{
    constexpr int CG = OUT / 4;
    constexpr int RGROUPS = 256 / CG;
    constexpr int ROWS = RGROUPS * 4;
    constexpr int LDK = 132;
    __shared__ float lds_a[ROWS][LDK];

    const int row0 = blockIdx.x * ROWS;
    const int col = (threadIdx.x % CG) * 4;
    const int rbase = (threadIdx.x / CG) * 4;

    for (int i = threadIdx.x * 4; i < ROWS * 128; i += 256 * 4) {
        const int r = i >> 7;
        const int k = i & 127;
        const int row = row0 + r;
        float4 v = make_float4(0.f, 0.f, 0.f, 0.f);
        if (row < nrows) {
            v = *reinterpret_cast<const float4*>(A + (size_t)row * 128 + k);
            if constexpr (SCALE) {
                const float s = inv_deg[row];
                v.x *= s; v.y *= s; v.z *= s; v.w *= s;
            }
        }
        *reinterpret_cast<float4*>(&lds_a[r][k]) = v;
    }
    __syncthreads();

    float acc[4][4] = {};
    #pragma unroll 4
    for (int k = 0; k < 128; ++k) {
        const float4 w = *reinterpret_cast<const float4*>(W + k * OUT + col);
        #pragma unroll
        for (int r = 0; r < 4; ++r) {
            const float a = lds_a[rbase + r][k];
            acc[r][0] += a * w.x;
            acc[r][1] += a * w.y;
            acc[r][2] += a * w.z;
            acc[r][3] += a * w.w;
        }
    }

    float4 bv = make_float4(0.f, 0.f, 0.f, 0.f);
    if constexpr (BIAS) bv = *reinterpret_cast<const float4*>(bias + col);
    #pragma unroll
    for (int r = 0; r < 4; ++r) {
        const int row = row0 + rbase + r;
        if (row >= nrows) continue;
        float4 o;
        o.x = acc[r][0] + bv.x;
        o.y = acc[r][1] + bv.y;
        o.z = acc[r][2] + bv.z;
        o.w = acc[r][3] + bv.w;
        if constexpr (RELU) {
            o.x = fmaxf(o.x, 0.f); o.y = fmaxf(o.y, 0.f);
            o.z = fmaxf(o.z, 0.f); o.w = fmaxf(o.w, 0.f);
        }
        if constexpr (OBF16) {
            ushortv4 ov;
            ov[0] = f2bf(o.x); ov[1] = f2bf(o.y);
            ov[2] = f2bf(o.z); ov[3] = f2bf(o.w);
            *reinterpret_cast<ushortv4*>(
                (unsigned short*)outv + (size_t)row * OUT + col) = ov;
        } else {
            *reinterpret_cast<float4*>(
                (float*)outv + (size_t)row * OUT + col) = o;
        }
    }
}

// ---------------------------------------------------------------------------
extern "C" void kernel_launch(void* const* d_in, const int* in_sizes, int n_in,
                              void* d_out, int out_size, void* d_ws, size_t ws_size,
                              hipStream_t stream)
{
    const float* x   = (const float*)d_in[0];
    const int*   src = (const int*)d_in[1];
    const int*   dst = (const int*)d_in[2];
    const float* W1  = (const float*)d_in[3];
    const float* b1  = (const float*)d_in[4];
    const float* W2  = (const float*)d_in[5];
    const float* b2  = (const float*)d_in[6];
    float* out = (float*)d_out;

    // Cumulative workspace layout (4B word offsets). offset_k = offset_{k-1} + size_{k-1}.
    //   name      offset      size (words)
    //   degi      0           50048
    //   invdeg    50048       50048
    //   rowStart  100096      50048   (needs 50001)
    //   blockSum  150144      256
    //   H         150400      51200   (200*256)
    //   LOFS      201600      51200
    //   csr       252800      800000
    //   tmp       1052800     800000
    //   xh        1852800     3200000 (50000*128 bf16 = 3.2M words; y2h aliases
    //                                  its first 1600000 words after gather1)
    //   aggA      5052800     6400000
    //   total     11452800 words = 45.8 MB
    float* ws  = (float*)d_ws;
    int*   wsi = (int*)d_ws;
    int*       degi     = wsi + 0;
    float*     invdeg   = ws  + 50048;
    int*       rowStart = wsi + 100096;
    int*       blockSum = wsi + 150144;
    int*       H        = wsi + 150400;
    int*       LOFS     = wsi + 201600;
    int*       csr      = wsi + 252800;
    unsigned*  tmp      = (unsigned*)(wsi + 1052800);
    ushortv8*  xh       = (ushortv8*)(wsi + 1852800);
    ushortv8*  y2h      = (ushortv8*)(wsi + 1852800);  // alias: xh dead after gather1
    float*     aggA     = ws  + 5052800;

    zero_kernel<<<SCAN_BLOCKS, 256, 0, stream>>>(degi, NNODES);

    const int eb = (NEDGES + 255) / 256;
    hist_kernel<<<eb, 256, 0, stream>>>(dst, degi, NEDGES);
    partial_kernel<<<SCAN_BLOCKS, 256, 0, stream>>>(degi, blockSum, NNODES);
    finalize_kernel<<<SCAN_BLOCKS, 256, 0, stream>>>(
        degi, blockSum, SCAN_BLOCKS, rowStart, invdeg, NNODES);
    partA_kernel<<<ABLOCKS, 256, 0, stream>>>(src, dst, tmp, H, LOFS, NEDGES);
    partB_kernel<<<SCAN_BLOCKS, 256, 0, stream>>>(
        tmp, H, LOFS, rowStart, csr, NNODES);

    // bf16 feature staging
    cast_kernel<<<(NNODES * 128 / 8 + 255) / 256, 256, 0, stream>>>(
        x, xh, NNODES * 128 / 8);

    // layer 1: aggregate xh, then in-place normalize+GEMM+bias+relu (fp32)
    gather_bf16_kernel<128, false><<<(NNODES + 3) / 4, 256, 0, stream>>>(
        xh, csr, rowStart, nullptr, nullptr, aggA, NNODES);
    gemm_kernel<128, true, true, true, false>
        <<<(NNODES + 31) / 32, 256, 0, stream>>>(
        aggA, invdeg, W1, b1, aggA, NNODES);

    // layer 2 (GEMM-first): y2h = bf16(h@W2), then aggregate+scale+bias
    // (y2h aliases xh — xh is dead after gather1 above)
    gemm_kernel<64, false, false, false, true>
        <<<(NNODES + 63) / 64, 256, 0, stream>>>(
        aggA, nullptr, W2, nullptr, y2h, NNODES);
    gather_bf16_kernel<64, true><<<(NNODES + 3) / 4, 256, 0, stream>>>(
        y2h, csr, rowStart, invdeg, b2, out, NNODES);
}

// Round 9
// 137.759 us; speedup vs baseline: 20.4011x; 1.4309x over previous
//
#include <hip/hip_runtime.h>

// GCN 2-layer, CSR-gather formulation, bf16 end-to-end intermediates + MFMA GEMMs.
// CSR build (fused, deterministic):
//   partA:      per-WG LDS hist+scan -> packed (src<<8|dst&255) into WG region
//               of tmp; stores H[w][b], LOFS[w][b]
//   bucketScan: 1 block; bucketStart[b] = excl-scan of column sums of H
//   partB:      per bucket: pass1 count per-node deg -> rowStart/inv_deg;
//               pass2 scatter src into csr window (LDS fill counters)
// Compute:
//   xh   = bf16(x);  Wt1/Wt2 = bf16(W^T)           [cast/prep kernels]
//   aggH = bf16(gather_sum(xh))                    [fp32 accum]
//   h    = bf16(relu((aggH*inv_deg)@W1+b1))        [MFMA 16x16x32 bf16]
//   y2h  = bf16(h@W2)                              [MFMA]
//   out  = gather_sum(y2h)*inv_deg + b2            [fp32 accum + epilogue]

constexpr int NNODES = 50000;
constexpr int NEDGES = 800000;
constexpr int SCAN_BLOCKS = (NNODES + 255) / 256;     // 196 == bucket count
constexpr int ABLOCKS = 200;                          // partA workgroups
constexpr int PER = (NEDGES + ABLOCKS - 1) / ABLOCKS; // 4000 edges per WG

typedef unsigned short ushortv8 __attribute__((ext_vector_type(8)));
typedef short bf16x8 __attribute__((ext_vector_type(8)));
typedef float f32x4 __attribute__((ext_vector_type(4)));

static __device__ __forceinline__ unsigned short f2bf(float f) {
    unsigned u = __float_as_uint(f);
    u += 0x7fff + ((u >> 16) & 1);  // round-to-nearest-even
    return (unsigned short)(u >> 16);
}
static __device__ __forceinline__ float bf2f(unsigned short h) {
    return __uint_as_float((unsigned)h << 16);
}

// ---------------------------------------------------------------------------
// partA: WG w owns edges [w*PER, ...); packs (src<<8 | dst&255) grouped by
// bucket (dst>>8) into its OWN tmp region via LDS hist + scan + cursors.
// ---------------------------------------------------------------------------
__global__ __launch_bounds__(256) void partA_kernel(
    const int* __restrict__ src, const int* __restrict__ dst,
    unsigned* __restrict__ tmp, int* __restrict__ H,
    int* __restrict__ LOFS, int nE)
{
    __shared__ int cnt[256];
    __shared__ int ofs[256];
    __shared__ int cur[256];
    const int t = threadIdx.x;
    cnt[t] = 0;
    __syncthreads();
    const int lo = blockIdx.x * PER;
    const int hi = min(lo + PER, nE);
    for (int i = lo + t; i < hi; i += 256)
        atomicAdd(&cnt[dst[i] >> 8], 1);
    __syncthreads();
    ofs[t] = cnt[t];
    __syncthreads();
    #pragma unroll
    for (int off = 1; off < 256; off <<= 1) {
        const int o = (t >= off) ? ofs[t - off] : 0;
        __syncthreads();
        ofs[t] += o;
        __syncthreads();
    }
    const int excl = ofs[t] - cnt[t];
    cur[t] = excl;
    H[blockIdx.x * 256 + t] = cnt[t];
    LOFS[blockIdx.x * 256 + t] = excl;
    __syncthreads();
    for (int i = lo + t; i < hi; i += 256) {
        const int d = dst[i];
        const unsigned pk = ((unsigned)src[i] << 8) | (unsigned)(d & 255);
        const int pos = lo + atomicAdd(&cur[d >> 8], 1);
        tmp[pos] = pk;
    }
}

// bucketStart[b] = exclusive scan over column sums of H (single block)
__global__ __launch_bounds__(256) void bucketScan_kernel(
    const int* __restrict__ H, int* __restrict__ bucketStart)
{
    __shared__ int s[256];
    const int t = threadIdx.x;
    int sum = 0;
    for (int w = 0; w < ABLOCKS; ++w) sum += H[w * 256 + t];
    s[t] = sum;
    __syncthreads();
    #pragma unroll
    for (int off = 1; off < 256; off <<= 1) {
        const int o = (t >= off) ? s[t - off] : 0;
        __syncthreads();
        s[t] += o;
        __syncthreads();
    }
    bucketStart[t] = s[t] - sum;  // exclusive
}

// ---------------------------------------------------------------------------
// partB: one WG per bucket. pass1: count per-node degrees -> rowStart/inv_deg;
// pass2: scatter src into the bucket's csr window via LDS fill counters.
// Entry location via binary-search merge over the 200 per-WG runs.
// ---------------------------------------------------------------------------
__global__ __launch_bounds__(256) void partB_kernel(
    const unsigned* __restrict__ tmp, const int* __restrict__ H,
    const int* __restrict__ LOFS, const int* __restrict__ bucketStart,
    int* __restrict__ csr, int* __restrict__ rowStart,
    float* __restrict__ inv_deg, int nNodes)
{
    __shared__ int pfx[ABLOCKS + 1];
    __shared__ int base[ABLOCKS];
    __shared__ int cnt[256];
    __shared__ int scn[256];
    __shared__ int fill[256];
    const int b = blockIdx.x;
    const int t = threadIdx.x;
    cnt[t] = 0;
    if (t < ABLOCKS) {
        pfx[t + 1] = H[t * 256 + b];
        base[t] = t * PER + LOFS[t * 256 + b];
    }
    if (t == 0) pfx[0] = 0;
    __syncthreads();
    if (t == 0) {
        int run = 0;
        for (int w = 0; w < ABLOCKS; ++w) { run += pfx[w + 1]; pfx[w + 1] = run; }
    }
    __syncthreads();
    const int total = pfx[ABLOCKS];
    // pass 1: per-node degree
    for (int j = t; j < total; j += 256) {
        int loW = 0, hiW = ABLOCKS;
        while (hiW - loW > 1) {
            const int mid = (loW + hiW) >> 1;
            if (pfx[mid] <= j) loW = mid; else hiW = mid;
        }
        const unsigned p = tmp[base[loW] + (j - pfx[loW])];
        atomicAdd(&cnt[p & 255u], 1);
    }
    __syncthreads();
    scn[t] = cnt[t];
    __syncthreads();
    #pragma unroll
    for (int off = 1; off < 256; off <<= 1) {
        const int o = (t >= off) ? scn[t - off] : 0;
        __syncthreads();
        scn[t] += o;
        __syncthreads();
    }
    const int gbase = bucketStart[b];
    const int excl = gbase + scn[t] - cnt[t];
    const int node = b * 256 + t;
    if (node < nNodes) {
        rowStart[node] = excl;
        inv_deg[node] = 1.0f / fmaxf((float)cnt[t], 1.0f);
    }
    if (b == 0 && t == 0) rowStart[nNodes] = NEDGES;
    fill[t] = excl;
    __syncthreads();
    // pass 2: scatter
    for (int j = t; j < total; j += 256) {
        int loW = 0, hiW = ABLOCKS;
        while (hiW - loW > 1) {
            const int mid = (loW + hiW) >> 1;
            if (pfx[mid] <= j) loW = mid; else hiW = mid;
        }
        const unsigned p = tmp[base[loW] + (j - pfx[loW])];
        const int pos = atomicAdd(&fill[p & 255u], 1);
        csr[pos] = (int)(p >> 8);
    }
}

// fp32 -> bf16 row cast, 8 elems/thread
__global__ __launch_bounds__(256) void cast_kernel(
    const float* __restrict__ in, ushortv8* __restrict__ outh, int n8)
{
    int i = blockIdx.x * 256 + threadIdx.x;
    if (i >= n8) return;
    const float4* p = reinterpret_cast<const float4*>(in) + (size_t)i * 2;
    const float4 a = p[0], b = p[1];
    ushortv8 v;
    v[0] = f2bf(a.x); v[1] = f2bf(a.y); v[2] = f2bf(a.z); v[3] = f2bf(a.w);
    v[4] = f2bf(b.x); v[5] = f2bf(b.y); v[6] = f2bf(b.z); v[7] = f2bf(b.w);
    outh[i] = v;
}

// Wt1[n][k] = bf16(W1[k][n]); Wt2[n][k] = bf16(W2[k][n]).
// Coalesced writes; reads uncoalesced but W is 96KB total, L2-hot.
__global__ __launch_bounds__(256) void prep_kernel(
    const float* __restrict__ W1, const float* __restrict__ W2,
    unsigned short* __restrict__ Wt1, unsigned short* __restrict__ Wt2)
{
    const int i = blockIdx.x * 256 + threadIdx.x;
    if (i < 128 * 128) {
        const int n = i >> 7, k = i & 127;
        Wt1[i] = f2bf(W1[k * 128 + n]);
    } else if (i < 128 * 128 + 64 * 128) {
        const int j = i - 128 * 128;
        const int n = j >> 7, k = j & 127;
        Wt2[j] = f2bf(W2[k * 64 + n]);
    }
}

// ---------------------------------------------------------------------------
// bf16-row gather-aggregate. One wave per dst node; 64 lanes =
// EPW edge-slots x LPR 8-elem column groups (16B/lane). fp32 accumulate,
// 2-deep edge unroll, shuffle-reduce, coalesced row write.
// EPI: fuse *inv_deg + bias (fp32 out). OBF16: emit bf16 row.
// ---------------------------------------------------------------------------
template<int F, bool EPI, bool OBF16>
__global__ __launch_bounds__(256) void gather_bf16_kernel(
    const ushortv8* __restrict__ feat, const int* __restrict__ csr,
    const int* __restrict__ rowStart, const float* __restrict__ inv_deg,
    const float* __restrict__ bias, void* __restrict__ outv, int nNodes)
{
    constexpr int LPR = F / 8;     // lanes per row: 16 (F=128) / 8 (F=64)
    constexpr int EPW = 64 / LPR;  // parallel edges per wave: 4 / 8
    const int wid = (blockIdx.x * 256 + threadIdx.x) >> 6;
    if (wid >= nNodes) return;
    const int lane = threadIdx.x & 63;
    const int eslot = lane / LPR;
    const int cg = lane % LPR;
    const int rs = rowStart[wid];
    const int re = rowStart[wid + 1];

    float acc0[8] = {}, acc1[8] = {};
    int j = rs + eslot;
    for (; j + EPW < re; j += 2 * EPW) {
        const int s0 = csr[j];
        const int s1 = csr[j + EPW];
        const ushortv8 v0 = feat[(size_t)s0 * LPR + cg];
        const ushortv8 v1 = feat[(size_t)s1 * LPR + cg];
        #pragma unroll
        for (int t = 0; t < 8; ++t) acc0[t] += bf2f(v0[t]);
        #pragma unroll
        for (int t = 0; t < 8; ++t) acc1[t] += bf2f(v1[t]);
    }
    if (j < re) {
        const int s0 = csr[j];
        const ushortv8 v0 = feat[(size_t)s0 * LPR + cg];
        #pragma unroll
        for (int t = 0; t < 8; ++t) acc0[t] += bf2f(v0[t]);
    }
    #pragma unroll
    for (int t = 0; t < 8; ++t) acc0[t] += acc1[t];

    #pragma unroll
    for (int off = LPR; off < 64; off <<= 1) {
        #pragma unroll
        for (int t = 0; t < 8; ++t) acc0[t] += __shfl_down(acc0[t], off, 64);
    }

    if (lane < LPR) {
        if constexpr (EPI) {
            const float s = inv_deg[wid];
            #pragma unroll
            for (int t = 0; t < 8; ++t) acc0[t] = acc0[t] * s + bias[cg * 8 + t];
        }
        if constexpr (OBF16) {
            ushortv8 ov;
            #pragma unroll
            for (int t = 0; t < 8; ++t) ov[t] = f2bf(acc0[t]);
            *reinterpret_cast<ushortv8*>(
                (unsigned short*)outv + (size_t)wid * F + cg * 8) = ov;
        } else {
            float* o = (float*)outv + (size_t)wid * F + cg * 8;
            *reinterpret_cast<float4*>(o) =
                make_float4(acc0[0], acc0[1], acc0[2], acc0[3]);
            *reinterpret_cast<float4*>(o + 4) =
                make_float4(acc0[4], acc0[5], acc0[6], acc0[7]);
        }
    }
}

// ---------------------------------------------------------------------------
// MFMA bf16 GEMM: out[r][n] = act( (A[r]*inv_deg[r]) @ W + b ), K=128.
// Block = 256 thr = 4 waves, 64 rows. A and Wt (pre-transposed W) staged to
// LDS bf16 with +8 pad. v_mfma_f32_16x16x32_bf16, 4 K-chunks x NT col-tiles.
// Fragment layout (m89-verified D; published A/B): A row=l&15 k=(l>>4)*8+j;
// B col=l&15 same k; D col=l&15 row=(l>>4)*4+q. Epilogue via LDS for
// coalesced bf16 stores.
// ---------------------------------------------------------------------------
template<int OUT, bool SCALE, bool BIAS, bool RELU>
__global__ __launch_bounds__(256) void mfma_gemm_kernel(
    const ushortv8* __restrict__ A,      // bf16 [nrows][16 chunks]
    const float* __restrict__ inv_deg,
    const ushortv8* __restrict__ Wt,     // bf16 [OUT][16 chunks]
    const float* __restrict__ bias,
    unsigned short* __restrict__ outh,   // bf16 [nrows][OUT]
    int nrows)
{
    constexpr int NT = OUT / 16;
    constexpr int LDK = 136;  // ushorts per LDS row (128 + 8 pad; 272B = 17x16B)
    __shared__ alignas(16) unsigned short lwt[OUT][LDK];
    __shared__ alignas(16) unsigned short la[64][LDK];

    const int row0 = blockIdx.x * 64;
    const int t = threadIdx.x;

    for (int i = t; i < OUT * 16; i += 256) {
        const int r = i >> 4, c = i & 15;
        *reinterpret_cast<ushortv8*>(&lwt[r][c * 8]) = Wt[i];
    }
    for (int i = t; i < 64 * 16; i += 256) {
        const int r = i >> 4, c = i & 15;
        const int row = row0 + r;
        ushortv8 v = {};
        if (row < nrows) {
            v = A[(size_t)row * 16 + c];
            if constexpr (SCALE) {
                const float s = inv_deg[row];
                #pragma unroll
                for (int jj = 0; jj < 8; ++jj) v[jj] = f2bf(bf2f(v[jj]) * s);
            }
        }
        *reinterpret_cast<ushortv8*>(&la[r][c * 8]) = v;
    }
    __syncthreads();

    const int wave = t >> 6, lane = t & 63;
    const int m = lane & 15, kg = lane >> 4;  // k-group 0..3

    f32x4 acc[NT] = {};
    #pragma unroll
    for (int kk = 0; kk < 4; ++kk) {
        const bf16x8 af =
            *reinterpret_cast<const bf16x8*>(&la[wave * 16 + m][kk * 32 + kg * 8]);
        #pragma unroll
        for (int n = 0; n < NT; ++n) {
            const bf16x8 bf =
                *reinterpret_cast<const bf16x8*>(&lwt[n * 16 + m][kk * 32 + kg * 8]);
            acc[n] = __builtin_amdgcn_mfma_f32_16x16x32_bf16(af, bf, acc[n], 0, 0, 0);
        }
    }

    __syncthreads();  // done with la; reuse as output staging [64][OUT+8]
    unsigned short* lo = &la[0][0];
    constexpr int LDO = OUT + 8;
    #pragma unroll
    for (int n = 0; n < NT; ++n) {
        float bv = 0.f;
        if constexpr (BIAS) bv = bias[n * 16 + m];
        #pragma unroll
        for (int q = 0; q < 4; ++q) {
            const int r = wave * 16 + kg * 4 + q;
            float v = acc[n][q] + bv;
            if constexpr (RELU) v = fmaxf(v, 0.f);
            lo[r * LDO + n * 16 + m] = f2bf(v);
        }
    }
    __syncthreads();
    for (int i = t; i < 64 * (OUT / 8); i += 256) {
        const int r = i / (OUT / 8), c = i % (OUT / 8);
        const int row = row0 + r;
        if (row < nrows)
            *reinterpret_cast<ushortv8*>(&outh[(size_t)row * OUT + c * 8]) =
                *reinterpret_cast<const ushortv8*>(&lo[r * LDO + c * 8]);
    }
}

// ---------------------------------------------------------------------------
extern "C" void kernel_launch(void* const* d_in, const int* in_sizes, int n_in,
                              void* d_out, int out_size, void* d_ws, size_t ws_size,
                              hipStream_t stream)
{
    const float* x   = (const float*)d_in[0];
    const int*   src = (const int*)d_in[1];
    const int*   dst = (const int*)d_in[2];
    const float* W1  = (const float*)d_in[3];
    const float* b1  = (const float*)d_in[4];
    const float* W2  = (const float*)d_in[5];
    const float* b2  = (const float*)d_in[6];
    float* out = (float*)d_out;

    // Cumulative workspace layout (4B word offsets); offset_k = off_{k-1}+size_{k-1}.
    //   name        offset     size
    //   rowStart    0          50048   (needs 50001)
    //   invdeg      50048      50048
    //   bucketStart 100096     256
    //   H           100352     51200   (200*256)
    //   LOFS        151552     51200
    //   csr         202752     800000
    //   tmp         1002752    800000
    //   Wt1         1802752    8192    (128*128 bf16)
    //   Wt2         1810944    4096    (64*128 bf16)
    //   xh          1815040    3200000 (50000*128 bf16)
    //   aggH        5015040    1600000 (50000*128 bf16)
    //   h           6615040    1600000 (50000*128 bf16)
    //   y2h         8215040    800000  (50000*64 bf16)
    //   end         9015040 words = 36.1 MB
    float* ws  = (float*)d_ws;
    int*   wsi = (int*)d_ws;
    int*            rowStart    = wsi + 0;
    float*          invdeg      = ws  + 50048;
    int*            bucketStart = wsi + 100096;
    int*            H           = wsi + 100352;
    int*            LOFS        = wsi + 151552;
    int*            csr         = wsi + 202752;
    unsigned*       tmp         = (unsigned*)(wsi + 1002752);
    unsigned short* Wt1         = (unsigned short*)(wsi + 1802752);
    unsigned short* Wt2         = (unsigned short*)(wsi + 1810944);
    ushortv8*       xh          = (ushortv8*)(wsi + 1815040);
    ushortv8*       aggH        = (ushortv8*)(wsi + 5015040);
    ushortv8*       h           = (ushortv8*)(wsi + 6615040);
    ushortv8*       y2h         = (ushortv8*)(wsi + 8215040);

    // CSR build (no global atomics on fp data, no degi/hist needed)
    partA_kernel<<<ABLOCKS, 256, 0, stream>>>(src, dst, tmp, H, LOFS, NEDGES);
    bucketScan_kernel<<<1, 256, 0, stream>>>(H, bucketStart);
    partB_kernel<<<SCAN_BLOCKS, 256, 0, stream>>>(
        tmp, H, LOFS, bucketStart, csr, rowStart, invdeg, NNODES);

    // staging casts
    cast_kernel<<<(NNODES * 128 / 8 + 255) / 256, 256, 0, stream>>>(
        x, xh, NNODES * 128 / 8);
    prep_kernel<<<(128 * 128 + 64 * 128 + 255) / 256, 256, 0, stream>>>(
        W1, W2, Wt1, Wt2);

    // layer 1: aggregate xh -> bf16 aggH; MFMA GEMM (scale+bias+relu) -> bf16 h
    gather_bf16_kernel<128, false, true><<<(NNODES + 3) / 4, 256, 0, stream>>>(
        xh, csr, rowStart, nullptr, nullptr, aggH, NNODES);
    mfma_gemm_kernel<128, true, true, true><<<(NNODES + 63) / 64, 256, 0, stream>>>(
        aggH, invdeg, (const ushortv8*)Wt1, b1, (unsigned short*)h, NNODES);

    // layer 2 (GEMM-first): y2h = bf16(h@W2); aggregate + scale + bias -> out
    mfma_gemm_kernel<64, false, false, false><<<(NNODES + 63) / 64, 256, 0, stream>>>(
        h, nullptr, (const ushortv8*)Wt2, nullptr, (unsigned short*)y2h, NNODES);
    gather_bf16_kernel<64, true, false><<<(NNODES + 3) / 4, 256, 0, stream>>>(
        y2h, csr, rowStart, invdeg, b2, out, NNODES);
}

// Round 13
// 123.142 us; speedup vs baseline: 22.8229x; 1.1187x over previous
//
#include <hip/hip_runtime.h>

// GCN 2-layer, CSR-gather formulation, bf16 intermediates + fused MFMA GEMMs.
// 5 launches:
//   setup  : [partA: per-WG bucket partition of edges] + [cast x->bf16] +
//            [prep: W1,W2 -> bf16 W^T]                    (independent, block-split)
//   partB  : per bucket: inline bucket-base scan; pass1 deg -> rowStart/inv_deg;
//            pass2 scatter src into csr window
//   gather<128> : aggH = bf16(gather_sum(xh))             [fp32 accum]
//   mfma_fused  : h = relu((aggH*inv)@W1+b1) in LDS; y2h = bf16(h@W2)
//   gather<64>  : out = gather_sum(y2h)*inv + b2
//
// r13 fix: r10-r12's deterministic absmax 0.1875 was a workspace layout bug —
// aggH (50000x128 bf16) needs 3.2M words, layout gave 1.6M, so y2h overlapped
// aggH rows 25000-37500 (mfma blocks clobbered rows other blocks still read).
// Layout is now a constexpr cumulative chain: hand arithmetic eliminated.

constexpr int NNODES = 50000;
constexpr int NEDGES = 800000;
constexpr int NBUCKETS = (NNODES + 255) / 256;        // 196
constexpr int ABLOCKS = 200;                          // partA workgroups
constexpr int PER = (NEDGES + ABLOCKS - 1) / ABLOCKS; // 4000 edges per WG
constexpr int NB_CAST = NNODES * 128 / 8 / 256;       // 3125
constexpr int NB_PREP = (128 * 128 + 64 * 128 + 255) / 256;  // 96

// ---- workspace layout, constexpr cumulative chain (units: 4B words) -------
constexpr size_t SZ_ROWSTART = 50048;                 // needs 50001
constexpr size_t SZ_INVDEG   = 50048;
constexpr size_t SZ_H        = (size_t)ABLOCKS * 256; // 51200
constexpr size_t SZ_LOFS     = (size_t)ABLOCKS * 256;
constexpr size_t SZ_CSR      = NEDGES;
constexpr size_t SZ_TMP      = NEDGES;
constexpr size_t SZ_WT1      = 128 * 128 / 2;         // bf16 -> words
constexpr size_t SZ_WT2      = 64 * 128 / 2;
constexpr size_t SZ_XH       = (size_t)NNODES * 128 / 2;  // 3,200,000
constexpr size_t SZ_AGGH     = (size_t)NNODES * 128 / 2;  // 3,200,000 (the r10-r12 bug: was 1.6M)
constexpr size_t SZ_Y2H      = (size_t)NNODES * 64 / 2;

constexpr size_t OFF_ROWSTART = 0;
constexpr size_t OFF_INVDEG   = OFF_ROWSTART + SZ_ROWSTART;
constexpr size_t OFF_H        = OFF_INVDEG   + SZ_INVDEG;
constexpr size_t OFF_LOFS     = OFF_H        + SZ_H;
constexpr size_t OFF_CSR      = OFF_LOFS     + SZ_LOFS;
constexpr size_t OFF_TMP      = OFF_CSR      + SZ_CSR;
constexpr size_t OFF_WT1      = OFF_TMP      + SZ_TMP;
constexpr size_t OFF_WT2      = OFF_WT1      + SZ_WT1;
constexpr size_t OFF_XH       = OFF_WT2      + SZ_WT2;
constexpr size_t OFF_AGGH     = OFF_XH       + SZ_XH;
constexpr size_t OFF_Y2H      = OFF_AGGH     + SZ_AGGH;
constexpr size_t WS_WORDS     = OFF_Y2H      + SZ_Y2H;   // 9,014,784 = 36.1 MB
static_assert(WS_WORDS < 11452800, "exceeds r7-proven workspace size");

typedef unsigned short ushortv8 __attribute__((ext_vector_type(8)));
typedef short bf16x8 __attribute__((ext_vector_type(8)));
typedef float f32x4 __attribute__((ext_vector_type(4)));

static __device__ __forceinline__ unsigned short f2bf(float f) {
    unsigned u = __float_as_uint(f);
    u += 0x7fff + ((u >> 16) & 1);  // round-to-nearest-even
    return (unsigned short)(u >> 16);
}
static __device__ __forceinline__ float bf2f(unsigned short h) {
    return __uint_as_float((unsigned)h << 16);
}

// ---------------------------------------------------------------------------
// setup: blocks [0,ABLOCKS) partA; [ABLOCKS, +NB_CAST) cast; rest prep.
// ---------------------------------------------------------------------------
__global__ __launch_bounds__(256) void setup_kernel(
    const int* __restrict__ src, const int* __restrict__ dst,
    unsigned* __restrict__ tmp, int* __restrict__ H, int* __restrict__ LOFS,
    const float* __restrict__ x, ushortv8* __restrict__ xh,
    const float* __restrict__ W1, const float* __restrict__ W2,
    unsigned short* __restrict__ Wt1, unsigned short* __restrict__ Wt2)
{
    const int blk = blockIdx.x;
    const int t = threadIdx.x;
    if (blk < ABLOCKS) {
        // ----- partA -----
        __shared__ int cnt[256];
        __shared__ int ofs[256];
        __shared__ int cur[256];
        cnt[t] = 0;
        __syncthreads();
        const int lo = blk * PER;
        const int hi = min(lo + PER, NEDGES);
        for (int i = lo + t; i < hi; i += 256)
            atomicAdd(&cnt[dst[i] >> 8], 1);
        __syncthreads();
        ofs[t] = cnt[t];
        __syncthreads();
        #pragma unroll
        for (int off = 1; off < 256; off <<= 1) {
            const int o = (t >= off) ? ofs[t - off] : 0;
            __syncthreads();
            ofs[t] += o;
            __syncthreads();
        }
        const int excl = ofs[t] - cnt[t];
        cur[t] = excl;
        H[blk * 256 + t] = cnt[t];
        LOFS[blk * 256 + t] = excl;
        __syncthreads();
        for (int i = lo + t; i < hi; i += 256) {
            const int d = dst[i];
            const unsigned pk = ((unsigned)src[i] << 8) | (unsigned)(d & 255);
            const int pos = lo + atomicAdd(&cur[d >> 8], 1);
            tmp[pos] = pk;
        }
    } else if (blk < ABLOCKS + NB_CAST) {
        // ----- cast x -> bf16, 8 elems/thread -----
        const int i = (blk - ABLOCKS) * 256 + t;  // < 800000 exactly
        const float4* p = reinterpret_cast<const float4*>(x) + (size_t)i * 2;
        const float4 a = p[0], b = p[1];
        ushortv8 v;
        v[0] = f2bf(a.x); v[1] = f2bf(a.y); v[2] = f2bf(a.z); v[3] = f2bf(a.w);
        v[4] = f2bf(b.x); v[5] = f2bf(b.y); v[6] = f2bf(b.z); v[7] = f2bf(b.w);
        xh[i] = v;
    } else {
        // ----- prep: Wt[n][k] = bf16(W[k][n]) -----
        const int i = (blk - ABLOCKS - NB_CAST) * 256 + t;
        if (i < 128 * 128) {
            const int n = i >> 7, k = i & 127;
            Wt1[i] = f2bf(W1[k * 128 + n]);
        } else if (i < 128 * 128 + 64 * 128) {
            const int j = i - 128 * 128;
            const int n = j >> 7, k = j & 127;
            Wt2[j] = f2bf(W2[k * 64 + n]);
        }
    }
}

// ---------------------------------------------------------------------------
// partB: one WG per bucket b. Inline bucket base (column-sum scan of H);
// run-prefix scan; pass1 per-node degree -> rowStart/inv_deg; pass2 scatter.
// ---------------------------------------------------------------------------
__global__ __launch_bounds__(256) void partB_kernel(
    const unsigned* __restrict__ tmp, const int* __restrict__ H,
    const int* __restrict__ LOFS, int* __restrict__ csr,
    int* __restrict__ rowStart, float* __restrict__ inv_deg, int nNodes)
{
    __shared__ int cs[256];    // column sums (bucket totals)
    __shared__ int s[256];     // scan scratch
    __shared__ int epfx[256];  // exclusive run prefix for this bucket
    __shared__ int base[256];  // run base addr in tmp
    __shared__ int cnt[256];
    __shared__ int fill[256];
    const int b = blockIdx.x;
    const int t = threadIdx.x;

    int sum = 0;
    for (int w = 0; w < ABLOCKS; ++w) sum += H[w * 256 + t];
    cs[t] = sum;
    s[t] = sum;
    __syncthreads();
    #pragma unroll
    for (int off = 1; off < 256; off <<= 1) {
        const int o = (t >= off) ? s[t - off] : 0;
        __syncthreads();
        s[t] += o;
        __syncthreads();
    }
    const int gbase = s[b] - cs[b];  // exclusive prefix at bucket b
    const int total = cs[b];
    __syncthreads();  // all threads read s[b] before s is reused

    const int hv = (t < ABLOCKS) ? H[t * 256 + b] : 0;
    s[t] = hv;
    if (t < ABLOCKS) base[t] = t * PER + LOFS[t * 256 + b];
    cnt[t] = 0;
    __syncthreads();
    #pragma unroll
    for (int off = 1; off < 256; off <<= 1) {
        const int o = (t >= off) ? s[t - off] : 0;
        __syncthreads();
        s[t] += o;
        __syncthreads();
    }
    epfx[t] = s[t] - hv;
    __syncthreads();

    // pass 1: per-node degree
    for (int j = t; j < total; j += 256) {
        int loW = 0, hiW = ABLOCKS;
        while (hiW - loW > 1) {
            const int mid = (loW + hiW) >> 1;
            if (epfx[mid] <= j) loW = mid; else hiW = mid;
        }
        const unsigned p = tmp[base[loW] + (j - epfx[loW])];
        atomicAdd(&cnt[p & 255u], 1);
    }
    __syncthreads();
    s[t] = cnt[t];
    __syncthreads();
    #pragma unroll
    for (int off = 1; off < 256; off <<= 1) {
        const int o = (t >= off) ? s[t - off] : 0;
        __syncthreads();
        s[t] += o;
        __syncthreads();
    }
    const int excl = gbase + s[t] - cnt[t];
    const int node = b * 256 + t;
    if (node < nNodes) {
        rowStart[node] = excl;
        inv_deg[node] = 1.0f / fmaxf((float)cnt[t], 1.0f);
    }
    if (b == 0 && t == 0) rowStart[nNodes] = NEDGES;
    fill[t] = excl;
    __syncthreads();

    // pass 2: scatter
    for (int j = t; j < total; j += 256) {
        int loW = 0, hiW = ABLOCKS;
        while (hiW - loW > 1) {
            const int mid = (loW + hiW) >> 1;
            if (epfx[mid] <= j) loW = mid; else hiW = mid;
        }
        const unsigned p = tmp[base[loW] + (j - epfx[loW])];
        const int pos = atomicAdd(&fill[p & 255u], 1);
        csr[pos] = (int)(p >> 8);
    }
}

// ---------------------------------------------------------------------------
// bf16-row gather-aggregate (unchanged, proven r4-r9).
// ---------------------------------------------------------------------------
template<int F, bool EPI, bool OBF16>
__global__ __launch_bounds__(256) void gather_bf16_kernel(
    const ushortv8* __restrict__ feat, const int* __restrict__ csr,
    const int* __restrict__ rowStart, const float* __restrict__ inv_deg,
    const float* __restrict__ bias, void* __restrict__ outv, int nNodes)
{
    constexpr int LPR = F / 8;     // lanes per row: 16 (F=128) / 8 (F=64)
    constexpr int EPW = 64 / LPR;  // parallel edges per wave: 4 / 8
    const int wid = (blockIdx.x * 256 + threadIdx.x) >> 6;
    if (wid >= nNodes) return;
    const int lane = threadIdx.x & 63;
    const int eslot = lane / LPR;
    const int cg = lane % LPR;
    const int rs = rowStart[wid];
    const int re = rowStart[wid + 1];

    float acc0[8] = {}, acc1[8] = {};
    int j = rs + eslot;
    for (; j + EPW < re; j += 2 * EPW) {
        const int s0 = csr[j];
        const int s1 = csr[j + EPW];
        const ushortv8 v0 = feat[(size_t)s0 * LPR + cg];
        const ushortv8 v1 = feat[(size_t)s1 * LPR + cg];
        #pragma unroll
        for (int t = 0; t < 8; ++t) acc0[t] += bf2f(v0[t]);
        #pragma unroll
        for (int t = 0; t < 8; ++t) acc1[t] += bf2f(v1[t]);
    }
    if (j < re) {
        const int s0 = csr[j];
        const ushortv8 v0 = feat[(size_t)s0 * LPR + cg];
        #pragma unroll
        for (int t = 0; t < 8; ++t) acc0[t] += bf2f(v0[t]);
    }
    #pragma unroll
    for (int t = 0; t < 8; ++t) acc0[t] += acc1[t];

    #pragma unroll
    for (int off = LPR; off < 64; off <<= 1) {
        #pragma unroll
        for (int t = 0; t < 8; ++t) acc0[t] += __shfl_down(acc0[t], off, 64);
    }

    if (lane < LPR) {
        if constexpr (EPI) {
            const float s = inv_deg[wid];
            #pragma unroll
            for (int t = 0; t < 8; ++t) acc0[t] = acc0[t] * s + bias[cg * 8 + t];
        }
        if constexpr (OBF16) {
            ushortv8 ov;
            #pragma unroll
            for (int t = 0; t < 8; ++t) ov[t] = f2bf(acc0[t]);
            *reinterpret_cast<ushortv8*>(
                (unsigned short*)outv + (size_t)wid * F + cg * 8) = ov;
        } else {
            float* o = (float*)outv + (size_t)wid * F + cg * 8;
            *reinterpret_cast<float4*>(o) =
                make_float4(acc0[0], acc0[1], acc0[2], acc0[3]);
            *reinterpret_cast<float4*>(o + 4) =
                make_float4(acc0[4], acc0[5], acc0[6], acc0[7]);
        }
    }
}

// ---------------------------------------------------------------------------
// Fused MFMA GEMMs, K=128, block = 4 waves = 64 rows:
//   h = relu((A*inv_deg)@Wt1^T + b1)   -> bf16, kept in LDS (la)
//   y2h = bf16(h@Wt2^T)                -> global
// v_mfma_f32_16x16x32_bf16; fragment layout as in r9 (HW-verified, passed).
// Barriers around the h handoff and la reuse kept from r11/r12 (safe).
// ---------------------------------------------------------------------------
__global__ __launch_bounds__(256) void mfma_fused_kernel(
    const ushortv8* __restrict__ A,      // aggH bf16 [nrows][16 chunks]
    const float* __restrict__ inv_deg,
    const ushortv8* __restrict__ Wt1,    // bf16 [128][16 chunks]
    const float* __restrict__ b1,
    const ushortv8* __restrict__ Wt2,    // bf16 [64][16 chunks]
    unsigned short* __restrict__ y2h,    // bf16 [nrows][64]
    int nrows)
{
    constexpr int LDK = 136;  // +8 bf16 pad
    __shared__ alignas(16) unsigned short lwt1[128][LDK];
    __shared__ alignas(16) unsigned short lwt2[64][LDK];
    __shared__ alignas(16) unsigned short la[64][LDK];

    const int row0 = blockIdx.x * 64;
    const int t = threadIdx.x;

    for (int i = t; i < 128 * 16; i += 256) {
        const int r = i >> 4, c = i & 15;
        *reinterpret_cast<ushortv8*>(&lwt1[r][c * 8]) = Wt1[i];
    }
    for (int i = t; i < 64 * 16; i += 256) {
        const int r = i >> 4, c = i & 15;
        *reinterpret_cast<ushortv8*>(&lwt2[r][c * 8]) = Wt2[i];
    }
    for (int i = t; i < 64 * 16; i += 256) {
        const int r = i >> 4, c = i & 15;
        const int row = row0 + r;
        ushortv8 v = {};
        if (row < nrows) {
            v = A[(size_t)row * 16 + c];
            const float s = inv_deg[row];
            #pragma unroll
            for (int jj = 0; jj < 8; ++jj) v[jj] = f2bf(bf2f(v[jj]) * s);
        }
        *reinterpret_cast<ushortv8*>(&la[r][c * 8]) = v;
    }
    __syncthreads();

    const int wave = t >> 6, lane = t & 63;
    const int m = lane & 15, kg = lane >> 4;  // k-group 0..3

    // GEMM1: 64x128 = (64x128) @ (128x128)
    f32x4 acc1[8] = {};
    #pragma unroll
    for (int kk = 0; kk < 4; ++kk) {
        const bf16x8 af =
            *reinterpret_cast<const bf16x8*>(&la[wave * 16 + m][kk * 32 + kg * 8]);
        #pragma unroll
        for (int n = 0; n < 8; ++n) {
            const bf16x8 bf =
                *reinterpret_cast<const bf16x8*>(&lwt1[n * 16 + m][kk * 32 + kg * 8]);
            acc1[n] = __builtin_amdgcn_mfma_f32_16x16x32_bf16(af, bf, acc1[n], 0, 0, 0);
        }
    }
    // epilogue1: h = bf16(relu(acc+b1)) into own la rows
    #pragma unroll
    for (int n = 0; n < 8; ++n) {
        const float bv = b1[n * 16 + m];
        #pragma unroll
        for (int q = 0; q < 4; ++q) {
            const int r = wave * 16 + kg * 4 + q;
            la[r][n * 16 + m] = f2bf(fmaxf(acc1[n][q] + bv, 0.f));
        }
    }
    __syncthreads();  // order h ds_writes before GEMM2 ds_reads

    // GEMM2: 64x64 = (64x128) @ (128x64)
    f32x4 acc2[4] = {};
    #pragma unroll
    for (int kk = 0; kk < 4; ++kk) {
        const bf16x8 af =
            *reinterpret_cast<const bf16x8*>(&la[wave * 16 + m][kk * 32 + kg * 8]);
        #pragma unroll
        for (int n = 0; n < 4; ++n) {
            const bf16x8 bf =
                *reinterpret_cast<const bf16x8*>(&lwt2[n * 16 + m][kk * 32 + kg * 8]);
            acc2[n] = __builtin_amdgcn_mfma_f32_16x16x32_bf16(af, bf, acc2[n], 0, 0, 0);
        }
    }
    __syncthreads();  // all GEMM2 reads of la complete before epilogue2 rewrites it
    // epilogue2: stage y2h bf16 into own la rows (cols 0..63)
    #pragma unroll
    for (int n = 0; n < 4; ++n) {
        #pragma unroll
        for (int q = 0; q < 4; ++q) {
            const int r = wave * 16 + kg * 4 + q;
            la[r][n * 16 + m] = f2bf(acc2[n][q]);
        }
    }
    __syncthreads();
    for (int i = t; i < 64 * 8; i += 256) {
        const int r = i >> 3, c = i & 7;
        const int row = row0 + r;
        if (row < nrows)
            *reinterpret_cast<ushortv8*>(&y2h[(size_t)row * 64 + c * 8]) =
                *reinterpret_cast<const ushortv8*>(&la[r][c * 8]);
    }
}

// ---------------------------------------------------------------------------
extern "C" void kernel_launch(void* const* d_in, const int* in_sizes, int n_in,
                              void* d_out, int out_size, void* d_ws, size_t ws_size,
                              hipStream_t stream)
{
    const float* x   = (const float*)d_in[0];
    const int*   src = (const int*)d_in[1];
    const int*   dst = (const int*)d_in[2];
    const float* W1  = (const float*)d_in[3];
    const float* b1  = (const float*)d_in[4];
    const float* W2  = (const float*)d_in[5];
    const float* b2  = (const float*)d_in[6];
    float* out = (float*)d_out;

    float* ws  = (float*)d_ws;
    int*   wsi = (int*)d_ws;
    int*            rowStart = wsi + OFF_ROWSTART;
    float*          invdeg   = ws  + OFF_INVDEG;
    int*            H        = wsi + OFF_H;
    int*            LOFS     = wsi + OFF_LOFS;
    int*            csr      = wsi + OFF_CSR;
    unsigned*       tmp      = (unsigned*)(wsi + OFF_TMP);
    unsigned short* Wt1      = (unsigned short*)(wsi + OFF_WT1);
    unsigned short* Wt2      = (unsigned short*)(wsi + OFF_WT2);
    ushortv8*       xh       = (ushortv8*)(wsi + OFF_XH);
    ushortv8*       aggH     = (ushortv8*)(wsi + OFF_AGGH);
    unsigned short* y2h      = (unsigned short*)(wsi + OFF_Y2H);

    // 1) partA + cast + prep (independent work, block-range split)
    setup_kernel<<<ABLOCKS + NB_CAST + NB_PREP, 256, 0, stream>>>(
        src, dst, tmp, H, LOFS, x, xh, W1, W2, Wt1, Wt2);

    // 2) CSR finalize per bucket (inline bucket-base scan)
    partB_kernel<<<NBUCKETS, 256, 0, stream>>>(
        tmp, H, LOFS, csr, rowStart, invdeg, NNODES);

    // 3) layer-1 aggregate -> bf16 aggH
    gather_bf16_kernel<128, false, true><<<(NNODES + 3) / 4, 256, 0, stream>>>(
        xh, csr, rowStart, nullptr, nullptr, aggH, NNODES);

    // 4) fused GEMM1(scale+bias+relu) + GEMM2 -> y2h
    mfma_fused_kernel<<<(NNODES + 63) / 64, 256, 0, stream>>>(
        aggH, invdeg, (const ushortv8*)Wt1, b1, (const ushortv8*)Wt2,
        y2h, NNODES);

    // 5) layer-2 aggregate + scale + bias -> out (fp32)
    gather_bf16_kernel<64, true, false><<<(NNODES + 3) / 4, 256, 0, stream>>>(
        (const ushortv8*)y2h, csr, rowStart, invdeg, b2, out, NNODES);
}